// Round 5
// baseline (605.784 us; speedup 1.0000x reference)
//
#include <hip/hip_runtime.h>

#define N_NODES 100000
#define N_EDGES 500000
#define N_GRAPHS 64
#define IN_DIM 512
#define HID 256
#define NREL 16

using short8 = __attribute__((ext_vector_type(8))) short;
using f32x4  = __attribute__((ext_vector_type(4))) float;

__device__ __forceinline__ unsigned short f2bf(float f) {
    union { float f; unsigned u; } v; v.f = f;
    unsigned u = v.u;
    unsigned r = u + 0x7FFF + ((u >> 16) & 1);
    return (unsigned short)(r >> 16);
}
__device__ __forceinline__ float bf2f(unsigned short h) {
    union { unsigned u; float f; } v; v.u = ((unsigned)h) << 16;
    return v.f;
}

__device__ __forceinline__ void gload_lds16(const unsigned short* g, unsigned short* l) {
    __builtin_amdgcn_global_load_lds(
        (const __attribute__((address_space(1))) void*)(g),
        (__attribute__((address_space(3))) void*)(l), 16, 0, 0);
}

// ---------------- conversions ----------------
__global__ void k_f2bf(const float* __restrict__ in, unsigned short* __restrict__ out, int n8) {
    int i = blockIdx.x * 256 + threadIdx.x;
    if (i >= n8) return;
    const float4* p = (const float4*)in + (size_t)i * 2;
    float4 a = p[0], b = p[1];
    ushort4 u0, u1;
    u0.x = f2bf(a.x); u0.y = f2bf(a.y); u0.z = f2bf(a.z); u0.w = f2bf(a.w);
    u1.x = f2bf(b.x); u1.y = f2bf(b.y); u1.z = f2bf(b.z); u1.w = f2bf(b.w);
    ushort4* q = (ushort4*)out + (size_t)i * 2;
    q[0] = u0; q[1] = u1;
}

// Wt[n][k] = bf16( n<HID ? Wrel[k][n] : Wroot[k][n-HID] ), n in [0,512)
__global__ void k_makeWt(const float* __restrict__ Wrel, const float* __restrict__ Wroot,
                         unsigned short* __restrict__ Wt, int K) {
    int n = blockIdx.x;
    const float* Wsrc = (n < HID) ? Wrel : Wroot;
    int col = n & (HID - 1);
    for (int k = threadIdx.x; k < K; k += 256)
        Wt[(size_t)n * K + k] = f2bf(Wsrc[(size_t)k * HID + col]);
}

// We2T[r][k], r<32, k<256: r<16 -> W_edge[k][r] (src half); r>=16 -> W_edge[256+k][r-16] (dst half)
__global__ void k_makeWe2T(const float* __restrict__ We, unsigned short* __restrict__ We2T) {
    int idx = blockIdx.x * 256 + threadIdx.x;
    if (idx >= 32 * 256) return;
    int r = idx >> 8, k = idx & 255;
    float v = (r < 16) ? We[k * NREL + r] : We[(256 + k) * NREL + (r - 16)];
    We2T[idx] = f2bf(v);
}

// ---------------- CSR build ----------------
__global__ void k_hist(const int* __restrict__ dstArr, int* __restrict__ counts) {
    int i = blockIdx.x * 256 + threadIdx.x;
    if (i < N_EDGES) atomicAdd(&counts[dstArr[i]], 1);
}

__global__ void k_scanA(const int* __restrict__ counts, int* __restrict__ bsum) {
    __shared__ int ws[4];
    int i = blockIdx.x * 256 + threadIdx.x;
    int v = (i < N_NODES) ? counts[i] : 0;
    for (int o = 32; o; o >>= 1) v += __shfl_down(v, o, 64);
    if ((threadIdx.x & 63) == 0) ws[threadIdx.x >> 6] = v;
    __syncthreads();
    if (threadIdx.x == 0) bsum[blockIdx.x] = ws[0] + ws[1] + ws[2] + ws[3];
}

__global__ void k_scanB(int* __restrict__ bsum, int nb) {
    __shared__ int buf[512];
    int t = threadIdx.x;
    for (int i = t; i < nb; i += 256) buf[i] = bsum[i];
    __syncthreads();
    if (t == 0) { int s = 0; for (int i = 0; i < nb; ++i) { int x = buf[i]; buf[i] = s; s += x; } }
    __syncthreads();
    for (int i = t; i < nb; i += 256) bsum[i] = buf[i];
}

__global__ void k_scanC(const int* __restrict__ counts, const int* __restrict__ bsum,
                        int* __restrict__ offsets, int* __restrict__ cur) {
    __shared__ int ws[4];
    int i = blockIdx.x * 256 + threadIdx.x;
    int lane = threadIdx.x & 63, wid = threadIdx.x >> 6;
    int v = (i < N_NODES) ? counts[i] : 0;
    int x = v;
    for (int o = 1; o < 64; o <<= 1) { int u = __shfl_up(x, o, 64); if (lane >= o) x += u; }
    if (lane == 63) ws[wid] = x;
    __syncthreads();
    if (threadIdx.x == 0) { int s = 0; for (int t = 0; t < 4; ++t) { int tt = ws[t]; ws[t] = s; s += tt; } }
    __syncthreads();
    x += ws[wid];
    x += bsum[blockIdx.x];
    if (i < N_NODES) { offsets[i + 1] = x; cur[i] = x - v; }
    if (i == 0) offsets[0] = 0;
}

__global__ void k_fill(const int* __restrict__ srcArr, const int* __restrict__ dstArr,
                       int* __restrict__ cur, int* __restrict__ csr) {
    int i = blockIdx.x * 256 + threadIdx.x;
    if (i < N_EDGES) {
        int p = atomicAdd(&cur[dstArr[i]], 1);
        csr[p] = srcArr[i];
    }
}

// ---------------- GEMM: [Yrel|Yroot][M x 256](bf16) = A[M x K] @ Bt[512 x K]^T ----------------
// Tile 256x128, BK=64, 512 threads (8 waves of 64x64), 3-slot LDS ring staged 2 K-tiles
// ahead, counted vmcnt (never 0 in steady state) + raw s_barrier (T3/T4 pattern).
// Slot layout: A [256][64] (16384 elems) then B [128][64] (8192 elems); XOR group swizzle
// (group kcp stored at kcp^(row&7)) via pre-swizzled global source, same as verified R2-R4.
template<int KDIM>
__global__ __launch_bounds__(512, 2) void k_gemm2(const unsigned short* __restrict__ A,
                                                  const unsigned short* __restrict__ Bt,
                                                  unsigned short* __restrict__ Yrel,
                                                  unsigned short* __restrict__ Yroot,
                                                  int M) {
    __shared__ unsigned short lds[3 * 24576];   // 144 KiB
    constexpr int NKT = KDIM / 64;
    const int tid  = threadIdx.x;
    const int lane = tid & 63;
    const int w    = tid >> 6;      // 0..7
    const int wm   = w >> 1;        // 0..3  (64-row band within 256)
    const int wn   = w & 1;         // 0..1  (64-col band within 128)

    // bijective XCD swizzle (m204 form; nwg need not be %8)
    int nwg = gridDim.x, orig = blockIdx.x;
    int q = nwg >> 3, r = nwg & 7;
    int xcd = orig & 7, local = orig >> 3;
    int id = (xcd < r ? xcd * (q + 1) : r * (q + 1) + (xcd - r) * q) + local;
    int bm0 = (id >> 2) * 256;      // 4 col-tiles per row-tile are consecutive ids -> same XCD
    int bn0 = (id & 3) * 128;

    auto stage = [&](int slot, int kt) {
        unsigned short* sA = lds + slot * 24576;
        unsigned short* sB = sA + 16384;
        const int k0 = kt << 6;
        #pragma unroll
        for (int it = 0; it < 4; ++it) {
            int c = (it << 9) + tid;
            int row = c >> 3, kcp = c & 7;
            int kcl = kcp ^ (row & 7);
            int gr = bm0 + row; if (gr >= M) gr = M - 1;
            gload_lds16(A + (size_t)gr * KDIM + k0 + kcl * 8,
                        sA + (size_t)((it << 9) + (w << 6)) * 8);
        }
        #pragma unroll
        for (int it = 0; it < 2; ++it) {
            int c = (it << 9) + tid;
            int row = c >> 3, kcp = c & 7;
            int kcl = kcp ^ (row & 7);
            gload_lds16(Bt + (size_t)(bn0 + row) * KDIM + k0 + kcl * 8,
                        sB + (size_t)((it << 9) + (w << 6)) * 8);
        }
    };

    f32x4 acc[4][4] = {};

    stage(0, 0);
    stage(1, 1);

    #pragma unroll
    for (int kt = 0; kt < NKT; ++kt) {
        if (kt + 2 < NKT) stage((kt + 2) % 3, kt + 2);
        // per-wave counted wait: 6 gload_lds per tile per thread; keep newest tiles in flight
        if (kt + 2 < NKT)      asm volatile("s_waitcnt vmcnt(12)" ::: "memory");
        else if (kt + 1 < NKT) asm volatile("s_waitcnt vmcnt(6)"  ::: "memory");
        else                   asm volatile("s_waitcnt vmcnt(0)"  ::: "memory");
        __builtin_amdgcn_s_barrier();
        __builtin_amdgcn_sched_barrier(0);

        const unsigned short* sA = lds + (kt % 3) * 24576;
        const unsigned short* sB = sA + 16384;
        #pragma unroll
        for (int kk = 0; kk < 2; ++kk) {
            short8 af[4], bfr[4];
            #pragma unroll
            for (int m = 0; m < 4; ++m) {
                int row = wm * 64 + m * 16 + (lane & 15);
                int g = ((kk << 2) + (lane >> 4)) ^ (row & 7);
                af[m] = *(const short8*)&sA[row * 64 + g * 8];
            }
            #pragma unroll
            for (int n = 0; n < 4; ++n) {
                int row = wn * 64 + n * 16 + (lane & 15);
                int g = ((kk << 2) + (lane >> 4)) ^ (row & 7);
                bfr[n] = *(const short8*)&sB[row * 64 + g * 8];
            }
            __builtin_amdgcn_s_setprio(1);
            #pragma unroll
            for (int m = 0; m < 4; ++m)
                #pragma unroll
                for (int n = 0; n < 4; ++n)
                    acc[m][n] = __builtin_amdgcn_mfma_f32_16x16x32_bf16(af[m], bfr[n], acc[m][n], 0, 0, 0);
            __builtin_amdgcn_s_setprio(0);
        }
        __builtin_amdgcn_s_barrier();
        __builtin_amdgcn_sched_barrier(0);
    }

    // epilogue: D row=(lane>>4)*4+i, col=lane&15 ; cols map to Yrel (bn0<256) or Yroot
    unsigned short* Cout = (bn0 < 256) ? Yrel : Yroot;
    int cb = bn0 & 255;
    #pragma unroll
    for (int m = 0; m < 4; ++m) {
        int row0 = bm0 + wm * 64 + m * 16 + ((lane >> 4) << 2);
        #pragma unroll
        for (int n = 0; n < 4; ++n) {
            int col = cb + wn * 64 + n * 16 + (lane & 15);
            #pragma unroll
            for (int i = 0; i < 4; ++i) {
                int rr = row0 + i;
                if (rr < M) Cout[(size_t)rr * 256 + col] = f2bf(acc[m][n][i]);
            }
        }
    }
}

// ---------------- fused aggregate + root + bias + ReLU -> bf16 ----------------
__global__ void k_combine(const unsigned short* __restrict__ yrel,
                          const unsigned short* __restrict__ yroot,
                          const int* __restrict__ offs,
                          const int* __restrict__ csr, const float* __restrict__ bias,
                          unsigned short* __restrict__ xout) {
    int node = blockIdx.x * 4 + (threadIdx.x >> 6);
    if (node >= N_NODES) return;
    int lane = threadIdx.x & 63;
    int d = lane * 4;
    float ax = 0.f, ay = 0.f, az = 0.f, aw = 0.f;
    int j0 = offs[node], j1 = offs[node + 1];
    for (int j = j0; j < j1; ++j) {
        int s = csr[j];
        ushort4 v = *(const ushort4*)(yrel + (size_t)s * 256 + d);
        ax += bf2f(v.x); ay += bf2f(v.y); az += bf2f(v.z); aw += bf2f(v.w);
    }
    ushort4 rr = *(const ushort4*)(yroot + (size_t)node * 256 + d);
    float4 bb = *(const float4*)(bias + d);
    ushort4 pk;
    pk.x = f2bf(fmaxf(ax + bf2f(rr.x) + bb.x, 0.f));
    pk.y = f2bf(fmaxf(ay + bf2f(rr.y) + bb.y, 0.f));
    pk.z = f2bf(fmaxf(az + bf2f(rr.z) + bb.z, 0.f));
    pk.w = f2bf(fmaxf(aw + bf2f(rr.w) + bb.w, 0.f));
    *(ushort4*)(xout + (size_t)node * HID + d) = pk;
}

// ---------------- edge head, stage 1: P[N x 32] = x3 @ We2T^T (fp32 out) ----------------
__global__ void k_proj(const unsigned short* __restrict__ x,   // [N][256] bf16
                       const unsigned short* __restrict__ We2T,// [32][256] bf16
                       float* __restrict__ P) {
    int lane = threadIdx.x & 63;
    int g = blockIdx.x * 4 + (threadIdx.x >> 6);   // wave id = 16-node tile
    if (g * 16 >= N_NODES) return;
    int n0 = g * 16;
    short8 bfr[2][8];
    #pragma unroll
    for (int cg = 0; cg < 2; ++cg)
        #pragma unroll
        for (int ks = 0; ks < 8; ++ks)
            bfr[cg][ks] = *(const short8*)&We2T[(size_t)(cg * 16 + (lane & 15)) * 256 + ks * 32 + ((lane >> 4) << 3)];
    f32x4 acc[2] = {};
    const size_t rb = (size_t)(n0 + (lane & 15)) * 256 + ((lane >> 4) << 3);
    #pragma unroll
    for (int ks = 0; ks < 8; ++ks) {
        short8 af = *(const short8*)&x[rb + ks * 32];
        acc[0] = __builtin_amdgcn_mfma_f32_16x16x32_bf16(af, bfr[0][ks], acc[0], 0, 0, 0);
        acc[1] = __builtin_amdgcn_mfma_f32_16x16x32_bf16(af, bfr[1][ks], acc[1], 0, 0, 0);
    }
    #pragma unroll
    for (int cg = 0; cg < 2; ++cg) {
        #pragma unroll
        for (int i = 0; i < 4; ++i) {
            int n = n0 + ((lane >> 4) << 2) + i;
            P[(size_t)n * 32 + cg * 16 + (lane & 15)] = acc[cg][i];
        }
    }
}

// ---------------- edge head, stage 2: out[e] = P[src][0:16] + P[dst][16:32] + b ----------
__global__ void k_edge_add(const float* __restrict__ P,
                           const int* __restrict__ srcArr, const int* __restrict__ dstArr,
                           const float* __restrict__ b_edge, float* __restrict__ out) {
    int e = blockIdx.x * 256 + threadIdx.x;
    if (e >= N_EDGES) return;
    int s = srcArr[e], d = dstArr[e];
    const float4* ps = (const float4*)(P + (size_t)s * 32);
    const float4* pd = (const float4*)(P + (size_t)d * 32 + 16);
    const float4* bb = (const float4*)b_edge;
    float4* po = (float4*)(out + (size_t)e * 16);
    #pragma unroll
    for (int i = 0; i < 4; ++i) {
        float4 a = ps[i], b = pd[i], c = bb[i];
        float4 rr;
        rr.x = a.x + b.x + c.x; rr.y = a.y + b.y + c.y;
        rr.z = a.z + b.z + c.z; rr.w = a.w + b.w + c.w;
        po[i] = rr;
    }
}

// ---------------- mean pool ----------------
__global__ void k_pool_sum(const unsigned short* __restrict__ x, const int* __restrict__ batch,
                           float* __restrict__ sums) {
    const int CH = 32;
    int w = threadIdx.x >> 6, lane = threadIdx.x & 63;
    int n0 = blockIdx.x * (4 * CH) + w * CH;
    if (n0 >= N_NODES) return;
    int n1 = n0 + CH; if (n1 > N_NODES) n1 = N_NODES;
    int d = lane * 4;
    float a0 = 0.f, a1 = 0.f, a2 = 0.f, a3 = 0.f;
    int gcur = batch[n0];
    for (int n = n0; n < n1; ++n) {
        int g = batch[n];
        if (g != gcur) {
            float* p = &sums[gcur * HID + d];
            atomicAdd(p + 0, a0); atomicAdd(p + 1, a1);
            atomicAdd(p + 2, a2); atomicAdd(p + 3, a3);
            a0 = a1 = a2 = a3 = 0.f; gcur = g;
        }
        ushort4 v = *(const ushort4*)&x[(size_t)n * HID + d];
        a0 += bf2f(v.x); a1 += bf2f(v.y); a2 += bf2f(v.z); a3 += bf2f(v.w);
    }
    float* p = &sums[gcur * HID + d];
    atomicAdd(p + 0, a0); atomicAdd(p + 1, a1);
    atomicAdd(p + 2, a2); atomicAdd(p + 3, a3);
}

__device__ __forceinline__ int lowerBound(const int* a, int n, int key) {
    int lo = 0, hi = n;
    while (lo < hi) { int mid = (lo + hi) >> 1; if (a[mid] < key) lo = mid + 1; else hi = mid; }
    return lo;
}

__global__ void k_pool_final(const float* __restrict__ sums, const int* __restrict__ batch,
                             float* __restrict__ out) {
    int g = blockIdx.x, d = threadIdx.x;
    int lo = lowerBound(batch, N_NODES, g);
    int hi = lowerBound(batch, N_NODES, g + 1);
    float cnt = (float)(hi - lo);
    out[(size_t)g * HID + d] = sums[g * HID + d] / fmaxf(cnt, 1.0f);
}

// ---------------- launcher ----------------
extern "C" void kernel_launch(void* const* d_in, const int* in_sizes, int n_in,
                              void* d_out, int out_size, void* d_ws, size_t ws_size,
                              hipStream_t stream) {
    const float* node_feats = (const float*)d_in[0];
    const int*   edge_index = (const int*)d_in[1];
    const int*   batch_idx  = (const int*)d_in[2];
    const float* W_rel0  = (const float*)d_in[3];
    const float* W_root0 = (const float*)d_in[4];
    const float* b0      = (const float*)d_in[5];
    const float* W_rel1  = (const float*)d_in[6];
    const float* W_root1 = (const float*)d_in[7];
    const float* b1      = (const float*)d_in[8];
    const float* W_rel2  = (const float*)d_in[9];
    const float* W_root2 = (const float*)d_in[10];
    const float* b2      = (const float*)d_in[11];
    const float* W_edge  = (const float*)d_in[12];
    const float* b_edge  = (const float*)d_in[13];

    const int* src = edge_index;
    const int* dst = edge_index + N_EDGES;

    char* ws = (char*)d_ws;
    size_t off = 0;
    auto alloc = [&](size_t bytes) -> char* {
        off = (off + 255) & ~(size_t)255;
        char* p = ws + off;
        off += bytes;
        return p;
    };
    unsigned short* bufA  = (unsigned short*)alloc((size_t)N_NODES * IN_DIM * 2); // x0b / x2b
    unsigned short* bufB  = (unsigned short*)alloc((size_t)N_NODES * HID * 2);    // x1b / x3b
    unsigned short* Yrel  = (unsigned short*)alloc((size_t)N_NODES * HID * 2);
    unsigned short* Yroot = (unsigned short*)alloc((size_t)N_NODES * HID * 2);
    unsigned short* Wt0   = (unsigned short*)alloc(512 * 512 * 2);
    unsigned short* Wt1   = (unsigned short*)alloc(512 * 256 * 2);
    unsigned short* Wt2   = (unsigned short*)alloc(512 * 256 * 2);
    unsigned short* We2T  = (unsigned short*)alloc(32 * 256 * 2);
    float* P     = (float*)alloc((size_t)N_NODES * 32 * 4);
    int* counts  = (int*)alloc((size_t)N_NODES * 4);
    int* offsets = (int*)alloc((size_t)(N_NODES + 1) * 4);
    int* cur     = (int*)alloc((size_t)N_NODES * 4);
    int* csr     = (int*)alloc((size_t)N_EDGES * 4);
    int* bsum    = (int*)alloc(512 * 4);
    float* sums  = (float*)alloc(N_GRAPHS * HID * 4);

    const int nscan = (N_NODES + 255) / 256; // 391

    hipMemsetAsync(counts, 0, (size_t)N_NODES * 4, stream);
    hipMemsetAsync(sums, 0, N_GRAPHS * HID * 4, stream);

    // conversions
    k_f2bf<<<(N_NODES * IN_DIM / 8 + 255) / 256, 256, 0, stream>>>(node_feats, bufA, N_NODES * IN_DIM / 8);
    k_makeWt<<<512, 256, 0, stream>>>(W_rel0, W_root0, Wt0, 512);
    k_makeWt<<<512, 256, 0, stream>>>(W_rel1, W_root1, Wt1, 256);
    k_makeWt<<<512, 256, 0, stream>>>(W_rel2, W_root2, Wt2, 256);
    k_makeWe2T<<<32, 256, 0, stream>>>(W_edge, We2T);

    // CSR build
    k_hist<<<(N_EDGES + 255) / 256, 256, 0, stream>>>(dst, counts);
    k_scanA<<<nscan, 256, 0, stream>>>(counts, bsum);
    k_scanB<<<1, 256, 0, stream>>>(bsum, nscan);
    k_scanC<<<nscan, 256, 0, stream>>>(counts, bsum, offsets, cur);
    k_fill<<<(N_EDGES + 255) / 256, 256, 0, stream>>>(src, dst, cur, csr);

    const int gemmGrid = ((N_NODES + 255) / 256) * 4; // 391*4 = 1564
    // layer 0
    k_gemm2<512><<<gemmGrid, 512, 0, stream>>>(bufA, Wt0, Yrel, Yroot, N_NODES);
    k_combine<<<(N_NODES + 3) / 4, 256, 0, stream>>>(Yrel, Yroot, offsets, csr, b0, bufB);
    // layer 1
    k_gemm2<256><<<gemmGrid, 512, 0, stream>>>(bufB, Wt1, Yrel, Yroot, N_NODES);
    k_combine<<<(N_NODES + 3) / 4, 256, 0, stream>>>(Yrel, Yroot, offsets, csr, b1, bufA);
    // layer 2
    k_gemm2<256><<<gemmGrid, 512, 0, stream>>>(bufA, Wt2, Yrel, Yroot, N_NODES);
    k_combine<<<(N_NODES + 3) / 4, 256, 0, stream>>>(Yrel, Yroot, offsets, csr, b2, bufB);

    // edge head -> d_out[0 : 8M)
    float* out_logits = (float*)d_out;
    k_proj<<<(N_NODES / 16 + 3) / 4, 256, 0, stream>>>(bufB, We2T, P);
    k_edge_add<<<(N_EDGES + 255) / 256, 256, 0, stream>>>(P, src, dst, b_edge, out_logits);

    // mean pool -> d_out[8M : 8M+16384)
    float* out_embed = (float*)d_out + (size_t)N_EDGES * NREL;
    k_pool_sum<<<(N_NODES + 127) / 128, 256, 0, stream>>>(bufB, batch_idx, sums);
    k_pool_final<<<N_GRAPHS, 256, 0, stream>>>(sums, batch_idx, out_embed);
}

// Round 6
// 544.798 us; speedup vs baseline: 1.1119x; 1.1119x over previous
//
#include <hip/hip_runtime.h>

#define N_NODES 100000
#define N_EDGES 500000
#define N_GRAPHS 64
#define IN_DIM 512
#define HID 256
#define NREL 16

using short8 = __attribute__((ext_vector_type(8))) short;
using f32x4  = __attribute__((ext_vector_type(4))) float;

__device__ __forceinline__ unsigned short f2bf(float f) {
    union { float f; unsigned u; } v; v.f = f;
    unsigned u = v.u;
    unsigned r = u + 0x7FFF + ((u >> 16) & 1);
    return (unsigned short)(r >> 16);
}
__device__ __forceinline__ float bf2f(unsigned short h) {
    union { unsigned u; float f; } v; v.u = ((unsigned)h) << 16;
    return v.f;
}

__device__ __forceinline__ void gload_lds16(const unsigned short* g, unsigned short* l) {
    __builtin_amdgcn_global_load_lds(
        (const __attribute__((address_space(1))) void*)(g),
        (__attribute__((address_space(3))) void*)(l), 16, 0, 0);
}

// ---------------- weight prep: Wt[n][k] = bf16(n<256 ? Wrel[k][n] : Wroot[k][n-256]) ----------
// Coalesced both sides via LDS 64x65 transpose tile. grid = dim3(K/64, 8), block 256.
__global__ void k_makeWt(const float* __restrict__ Wrel, const float* __restrict__ Wroot,
                         unsigned short* __restrict__ Wt, int K) {
    __shared__ float t[64][65];
    int tid = threadIdx.x;
    int tk = blockIdx.x * 64, tn = blockIdx.y * 64;
    const float* Wsrc = (tn < 256) ? Wrel : Wroot;
    int col0 = tn & 255;
    #pragma unroll
    for (int r = 0; r < 16; ++r) {
        int kl = r * 4 + (tid >> 6);
        int nl = tid & 63;
        t[kl][nl] = Wsrc[(size_t)(tk + kl) * 256 + col0 + nl];
    }
    __syncthreads();
    #pragma unroll
    for (int r = 0; r < 16; ++r) {
        int nl = r * 4 + (tid >> 6);
        int kl = tid & 63;
        Wt[(size_t)(tn + nl) * K + tk + kl] = f2bf(t[kl][nl]);
    }
}

// We2T[r][k], r<32, k<256: r<16 -> W_edge[k][r] (src half); r>=16 -> W_edge[256+k][r-16]
__global__ void k_makeWe2T(const float* __restrict__ We, unsigned short* __restrict__ We2T) {
    int idx = blockIdx.x * 256 + threadIdx.x;
    if (idx >= 32 * 256) return;
    int r = idx >> 8, k = idx & 255;
    float v = (r < 16) ? We[k * NREL + r] : We[(256 + k) * NREL + (r - 16)];
    We2T[idx] = f2bf(v);
}

// ---------------- CSR build ----------------
__global__ void k_hist(const int* __restrict__ dstArr, int* __restrict__ counts) {
    int i = blockIdx.x * 256 + threadIdx.x;
    if (i < N_EDGES) atomicAdd(&counts[dstArr[i]], 1);
}

__global__ void k_scanA(const int* __restrict__ counts, int* __restrict__ bsum) {
    __shared__ int ws[4];
    int i = blockIdx.x * 256 + threadIdx.x;
    int v = (i < N_NODES) ? counts[i] : 0;
    for (int o = 32; o; o >>= 1) v += __shfl_down(v, o, 64);
    if ((threadIdx.x & 63) == 0) ws[threadIdx.x >> 6] = v;
    __syncthreads();
    if (threadIdx.x == 0) bsum[blockIdx.x] = ws[0] + ws[1] + ws[2] + ws[3];
}

__global__ void k_scanB(int* __restrict__ bsum, int nb) {
    __shared__ int buf[512];
    int t = threadIdx.x;
    for (int i = t; i < nb; i += 256) buf[i] = bsum[i];
    __syncthreads();
    if (t == 0) { int s = 0; for (int i = 0; i < nb; ++i) { int x = buf[i]; buf[i] = s; s += x; } }
    __syncthreads();
    for (int i = t; i < nb; i += 256) bsum[i] = buf[i];
}

__global__ void k_scanC(const int* __restrict__ counts, const int* __restrict__ bsum,
                        int* __restrict__ offsets, int* __restrict__ cur) {
    __shared__ int ws[4];
    int i = blockIdx.x * 256 + threadIdx.x;
    int lane = threadIdx.x & 63, wid = threadIdx.x >> 6;
    int v = (i < N_NODES) ? counts[i] : 0;
    int x = v;
    for (int o = 1; o < 64; o <<= 1) { int u = __shfl_up(x, o, 64); if (lane >= o) x += u; }
    if (lane == 63) ws[wid] = x;
    __syncthreads();
    if (threadIdx.x == 0) { int s = 0; for (int t = 0; t < 4; ++t) { int tt = ws[t]; ws[t] = s; s += tt; } }
    __syncthreads();
    x += ws[wid];
    x += bsum[blockIdx.x];
    if (i < N_NODES) { offsets[i + 1] = x; cur[i] = x - v; }
    if (i == 0) offsets[0] = 0;
}

__global__ void k_fill(const int* __restrict__ srcArr, const int* __restrict__ dstArr,
                       int* __restrict__ cur, int* __restrict__ csr) {
    int i = blockIdx.x * 256 + threadIdx.x;
    if (i < N_EDGES) {
        int p = atomicAdd(&cur[dstArr[i]], 1);
        csr[p] = srcArr[i];
    }
}

// ---------------- GEMM (bf16 A): [Yrel|Yroot][M x 256] = A[M x K] @ Bt[512 x K]^T ----------
// Verified R4 structure: 128x128 tile, 4 waves, gload_lds16 staging, XOR group swizzle.
__global__ __launch_bounds__(256) void k_gemm(const unsigned short* __restrict__ A,
                                              const unsigned short* __restrict__ Bt,
                                              unsigned short* __restrict__ Yrel,
                                              unsigned short* __restrict__ Yroot,
                                              int M, int K) {
    __shared__ unsigned short lds[2 * 128 * 64];
    const int tid  = threadIdx.x;
    const int lane = tid & 63;
    const int w    = tid >> 6;
    const int wm   = w >> 1, wn = w & 1;

    int nwg  = gridDim.x;
    int orig = blockIdx.x;
    int q    = nwg >> 3;
    int id   = (orig & 7) * q + (orig >> 3);
    int bm0  = (id >> 2) * 128;
    int bn0  = (id & 3) * 128;

    f32x4 acc[4][4] = {};

    const int nkt = K >> 6;
    for (int kt = 0; kt < nkt; ++kt) {
        int k0 = kt << 6;
        #pragma unroll
        for (int it = 0; it < 4; ++it) {
            int c = (it << 8) + tid;
            int row = c >> 3, kcp = c & 7;
            int kcl = kcp ^ (row & 7);
            int gr = bm0 + row; gr = (gr < M) ? gr : (M - 1);
            gload_lds16(A + (size_t)gr * K + k0 + kcl * 8,
                        &lds[(size_t)((it << 8) + (w << 6)) * 8]);
        }
        #pragma unroll
        for (int it = 0; it < 4; ++it) {
            int c = (it << 8) + tid;
            int row = c >> 3, kcp = c & 7;
            int kcl = kcp ^ (row & 7);
            gload_lds16(Bt + (size_t)(bn0 + row) * K + k0 + kcl * 8,
                        &lds[128 * 64 + (size_t)((it << 8) + (w << 6)) * 8]);
        }
        __syncthreads();
        #pragma unroll
        for (int kk = 0; kk < 2; ++kk) {
            short8 af[4], bfr[4];
            #pragma unroll
            for (int m = 0; m < 4; ++m) {
                int row = wm * 64 + m * 16 + (lane & 15);
                int g = ((kk << 2) + (lane >> 4)) ^ (row & 7);
                af[m] = *(const short8*)&lds[row * 64 + g * 8];
            }
            #pragma unroll
            for (int n = 0; n < 4; ++n) {
                int row = wn * 64 + n * 16 + (lane & 15);
                int g = ((kk << 2) + (lane >> 4)) ^ (row & 7);
                bfr[n] = *(const short8*)&lds[128 * 64 + row * 64 + g * 8];
            }
            #pragma unroll
            for (int m = 0; m < 4; ++m)
                #pragma unroll
                for (int n = 0; n < 4; ++n)
                    acc[m][n] = __builtin_amdgcn_mfma_f32_16x16x32_bf16(af[m], bfr[n], acc[m][n], 0, 0, 0);
        }
        __syncthreads();
    }
    unsigned short* Cout = (bn0 < 256) ? Yrel : Yroot;
    int cb = bn0 & 255;
    #pragma unroll
    for (int m = 0; m < 4; ++m) {
        int row0 = bm0 + wm * 64 + m * 16 + ((lane >> 4) << 2);
        #pragma unroll
        for (int n = 0; n < 4; ++n) {
            int col = cb + wn * 64 + n * 16 + (lane & 15);
            #pragma unroll
            for (int i = 0; i < 4; ++i) {
                int r = row0 + i;
                if (r < M) Cout[(size_t)r * 256 + col] = f2bf(acc[m][n][i]);
            }
        }
    }
}

// ---------------- GEMM L0 (fp32 A, fused f2bf): K = 512 fixed ----------------
// A staged via reg: float4 load -> cvt bf16 -> ds_write_b64 at swizzled offset.
__global__ __launch_bounds__(256) void k_gemm0(const float* __restrict__ A,
                                               const unsigned short* __restrict__ Bt,
                                               unsigned short* __restrict__ Yrel,
                                               unsigned short* __restrict__ Yroot,
                                               int M) {
    constexpr int K = 512;
    __shared__ unsigned short lds[2 * 128 * 64];
    const int tid  = threadIdx.x;
    const int lane = tid & 63;
    const int w    = tid >> 6;
    const int wm   = w >> 1, wn = w & 1;

    int nwg  = gridDim.x;
    int orig = blockIdx.x;
    int q    = nwg >> 3;
    int id   = (orig & 7) * q + (orig >> 3);
    int bm0  = (id >> 2) * 128;
    int bn0  = (id & 3) * 128;

    f32x4 acc[4][4] = {};

    const int nkt = K >> 6;
    for (int kt = 0; kt < nkt; ++kt) {
        int k0 = kt << 6;
        // B tile via gload_lds (bf16 weights)
        #pragma unroll
        for (int it = 0; it < 4; ++it) {
            int c = (it << 8) + tid;
            int row = c >> 3, kcp = c & 7;
            int kcl = kcp ^ (row & 7);
            gload_lds16(Bt + (size_t)(bn0 + row) * K + k0 + kcl * 8,
                        &lds[128 * 64 + (size_t)((it << 8) + (w << 6)) * 8]);
        }
        // A tile from fp32, converted in-flight; ds_write to swizzled offset
        #pragma unroll
        for (int it = 0; it < 8; ++it) {
            int c = (it << 8) + tid;      // 0..2047 float4 slots
            int row = c >> 4;             // 0..127
            int f4  = c & 15;             // which float4 within 64-elem row
            int gr = bm0 + row; gr = (gr < M) ? gr : (M - 1);
            float4 v = *(const float4*)(A + (size_t)gr * K + k0 + f4 * 4);
            ushort4 u;
            u.x = f2bf(v.x); u.y = f2bf(v.y); u.z = f2bf(v.z); u.w = f2bf(v.w);
            int g = (f4 >> 1) ^ (row & 7);
            *(ushort4*)&lds[row * 64 + g * 8 + (f4 & 1) * 4] = u;
        }
        __syncthreads();
        #pragma unroll
        for (int kk = 0; kk < 2; ++kk) {
            short8 af[4], bfr[4];
            #pragma unroll
            for (int m = 0; m < 4; ++m) {
                int row = wm * 64 + m * 16 + (lane & 15);
                int g = ((kk << 2) + (lane >> 4)) ^ (row & 7);
                af[m] = *(const short8*)&lds[row * 64 + g * 8];
            }
            #pragma unroll
            for (int n = 0; n < 4; ++n) {
                int row = wn * 64 + n * 16 + (lane & 15);
                int g = ((kk << 2) + (lane >> 4)) ^ (row & 7);
                bfr[n] = *(const short8*)&lds[128 * 64 + row * 64 + g * 8];
            }
            #pragma unroll
            for (int m = 0; m < 4; ++m)
                #pragma unroll
                for (int n = 0; n < 4; ++n)
                    acc[m][n] = __builtin_amdgcn_mfma_f32_16x16x32_bf16(af[m], bfr[n], acc[m][n], 0, 0, 0);
        }
        __syncthreads();
    }
    unsigned short* Cout = (bn0 < 256) ? Yrel : Yroot;
    int cb = bn0 & 255;
    #pragma unroll
    for (int m = 0; m < 4; ++m) {
        int row0 = bm0 + wm * 64 + m * 16 + ((lane >> 4) << 2);
        #pragma unroll
        for (int n = 0; n < 4; ++n) {
            int col = cb + wn * 64 + n * 16 + (lane & 15);
            #pragma unroll
            for (int i = 0; i < 4; ++i) {
                int r = row0 + i;
                if (r < M) Cout[(size_t)r * 256 + col] = f2bf(acc[m][n][i]);
            }
        }
    }
}

// ---------------- fused aggregate + root + bias + ReLU -> bf16 (4-way ILP) ----------------
__device__ __forceinline__ void acc4(float4& a, ushort4 v) {
    a.x += bf2f(v.x); a.y += bf2f(v.y); a.z += bf2f(v.z); a.w += bf2f(v.w);
}

__global__ void k_combine(const unsigned short* __restrict__ yrel,
                          const unsigned short* __restrict__ yroot,
                          const int* __restrict__ offs,
                          const int* __restrict__ csr, const float* __restrict__ bias,
                          unsigned short* __restrict__ xout) {
    int node = blockIdx.x * 4 + (threadIdx.x >> 6);
    if (node >= N_NODES) return;
    int lane = threadIdx.x & 63;
    int d = lane * 4;
    int j0 = offs[node], j1 = offs[node + 1];
    float4 a0 = {0,0,0,0}, a1 = {0,0,0,0}, a2 = {0,0,0,0}, a3 = {0,0,0,0};
    int j = j0;
    for (; j + 4 <= j1; j += 4) {
        int s0 = csr[j], s1 = csr[j + 1], s2 = csr[j + 2], s3 = csr[j + 3];
        ushort4 v0 = *(const ushort4*)(yrel + (size_t)s0 * 256 + d);
        ushort4 v1 = *(const ushort4*)(yrel + (size_t)s1 * 256 + d);
        ushort4 v2 = *(const ushort4*)(yrel + (size_t)s2 * 256 + d);
        ushort4 v3 = *(const ushort4*)(yrel + (size_t)s3 * 256 + d);
        acc4(a0, v0); acc4(a1, v1); acc4(a2, v2); acc4(a3, v3);
    }
    for (; j < j1; ++j) {
        int s = csr[j];
        acc4(a0, *(const ushort4*)(yrel + (size_t)s * 256 + d));
    }
    a0.x += a1.x + a2.x + a3.x;
    a0.y += a1.y + a2.y + a3.y;
    a0.z += a1.z + a2.z + a3.z;
    a0.w += a1.w + a2.w + a3.w;
    ushort4 rr = *(const ushort4*)(yroot + (size_t)node * 256 + d);
    float4 bb = *(const float4*)(bias + d);
    ushort4 pk;
    pk.x = f2bf(fmaxf(a0.x + bf2f(rr.x) + bb.x, 0.f));
    pk.y = f2bf(fmaxf(a0.y + bf2f(rr.y) + bb.y, 0.f));
    pk.z = f2bf(fmaxf(a0.z + bf2f(rr.z) + bb.z, 0.f));
    pk.w = f2bf(fmaxf(a0.w + bf2f(rr.w) + bb.w, 0.f));
    *(ushort4*)(xout + (size_t)node * HID + d) = pk;
}

// ---------------- edge head, stage 1: P[N x 32] = x3 @ We2T^T (fp32 out) ----------------
__global__ void k_proj(const unsigned short* __restrict__ x,
                       const unsigned short* __restrict__ We2T,
                       float* __restrict__ P) {
    int lane = threadIdx.x & 63;
    int g = blockIdx.x * 4 + (threadIdx.x >> 6);
    if (g * 16 >= N_NODES) return;
    int n0 = g * 16;
    short8 bfr[2][8];
    #pragma unroll
    for (int cg = 0; cg < 2; ++cg)
        #pragma unroll
        for (int ks = 0; ks < 8; ++ks)
            bfr[cg][ks] = *(const short8*)&We2T[(size_t)(cg * 16 + (lane & 15)) * 256 + ks * 32 + ((lane >> 4) << 3)];
    f32x4 acc[2] = {};
    const size_t rb = (size_t)(n0 + (lane & 15)) * 256 + ((lane >> 4) << 3);
    #pragma unroll
    for (int ks = 0; ks < 8; ++ks) {
        short8 af = *(const short8*)&x[rb + ks * 32];
        acc[0] = __builtin_amdgcn_mfma_f32_16x16x32_bf16(af, bfr[0][ks], acc[0], 0, 0, 0);
        acc[1] = __builtin_amdgcn_mfma_f32_16x16x32_bf16(af, bfr[1][ks], acc[1], 0, 0, 0);
    }
    #pragma unroll
    for (int cg = 0; cg < 2; ++cg) {
        #pragma unroll
        for (int i = 0; i < 4; ++i) {
            int n = n0 + ((lane >> 4) << 2) + i;
            P[(size_t)n * 32 + cg * 16 + (lane & 15)] = acc[cg][i];
        }
    }
}

// ---------------- edge head, stage 2: out[e] = P[src][0:16] + P[dst][16:32] + b ----------
__global__ void k_edge_add(const float* __restrict__ P,
                           const int* __restrict__ srcArr, const int* __restrict__ dstArr,
                           const float* __restrict__ b_edge, float* __restrict__ out) {
    int e = blockIdx.x * 256 + threadIdx.x;
    if (e >= N_EDGES) return;
    int s = srcArr[e], d = dstArr[e];
    const float4* ps = (const float4*)(P + (size_t)s * 32);
    const float4* pd = (const float4*)(P + (size_t)d * 32 + 16);
    const float4* bb = (const float4*)b_edge;
    float4* po = (float4*)(out + (size_t)e * 16);
    #pragma unroll
    for (int i = 0; i < 4; ++i) {
        float4 a = ps[i], b = pd[i], c = bb[i];
        float4 rr;
        rr.x = a.x + b.x + c.x; rr.y = a.y + b.y + c.y;
        rr.z = a.z + b.z + c.z; rr.w = a.w + b.w + c.w;
        po[i] = rr;
    }
}

// ---------------- mean pool ----------------
__global__ void k_pool_sum(const unsigned short* __restrict__ x, const int* __restrict__ batch,
                           float* __restrict__ sums) {
    const int CH = 32;
    int w = threadIdx.x >> 6, lane = threadIdx.x & 63;
    int n0 = blockIdx.x * (4 * CH) + w * CH;
    if (n0 >= N_NODES) return;
    int n1 = n0 + CH; if (n1 > N_NODES) n1 = N_NODES;
    int d = lane * 4;
    float a0 = 0.f, a1 = 0.f, a2 = 0.f, a3 = 0.f;
    int gcur = batch[n0];
    for (int n = n0; n < n1; ++n) {
        int g = batch[n];
        if (g != gcur) {
            float* p = &sums[gcur * HID + d];
            atomicAdd(p + 0, a0); atomicAdd(p + 1, a1);
            atomicAdd(p + 2, a2); atomicAdd(p + 3, a3);
            a0 = a1 = a2 = a3 = 0.f; gcur = g;
        }
        ushort4 v = *(const ushort4*)&x[(size_t)n * HID + d];
        a0 += bf2f(v.x); a1 += bf2f(v.y); a2 += bf2f(v.z); a3 += bf2f(v.w);
    }
    float* p = &sums[gcur * HID + d];
    atomicAdd(p + 0, a0); atomicAdd(p + 1, a1);
    atomicAdd(p + 2, a2); atomicAdd(p + 3, a3);
}

__device__ __forceinline__ int lowerBound(const int* a, int n, int key) {
    int lo = 0, hi = n;
    while (lo < hi) { int mid = (lo + hi) >> 1; if (a[mid] < key) lo = mid + 1; else hi = mid; }
    return lo;
}

__global__ void k_pool_final(const float* __restrict__ sums, const int* __restrict__ batch,
                             float* __restrict__ out) {
    int g = blockIdx.x, d = threadIdx.x;
    int lo = lowerBound(batch, N_NODES, g);
    int hi = lowerBound(batch, N_NODES, g + 1);
    float cnt = (float)(hi - lo);
    out[(size_t)g * HID + d] = sums[g * HID + d] / fmaxf(cnt, 1.0f);
}

// ---------------- launcher ----------------
extern "C" void kernel_launch(void* const* d_in, const int* in_sizes, int n_in,
                              void* d_out, int out_size, void* d_ws, size_t ws_size,
                              hipStream_t stream) {
    const float* node_feats = (const float*)d_in[0];
    const int*   edge_index = (const int*)d_in[1];
    const int*   batch_idx  = (const int*)d_in[2];
    const float* W_rel0  = (const float*)d_in[3];
    const float* W_root0 = (const float*)d_in[4];
    const float* b0      = (const float*)d_in[5];
    const float* W_rel1  = (const float*)d_in[6];
    const float* W_root1 = (const float*)d_in[7];
    const float* b1      = (const float*)d_in[8];
    const float* W_rel2  = (const float*)d_in[9];
    const float* W_root2 = (const float*)d_in[10];
    const float* b2      = (const float*)d_in[11];
    const float* W_edge  = (const float*)d_in[12];
    const float* b_edge  = (const float*)d_in[13];

    const int* src = edge_index;
    const int* dst = edge_index + N_EDGES;

    char* ws = (char*)d_ws;
    size_t off = 0;
    auto alloc = [&](size_t bytes) -> char* {
        off = (off + 255) & ~(size_t)255;
        char* p = ws + off;
        off += bytes;
        return p;
    };
    unsigned short* xA    = (unsigned short*)alloc((size_t)N_NODES * HID * 2);  // x2
    unsigned short* xB    = (unsigned short*)alloc((size_t)N_NODES * HID * 2);  // x1 / x3
    unsigned short* Yrel  = (unsigned short*)alloc((size_t)N_NODES * HID * 2);
    unsigned short* Yroot = (unsigned short*)alloc((size_t)N_NODES * HID * 2);
    unsigned short* Wt0   = (unsigned short*)alloc(512 * 512 * 2);
    unsigned short* Wt1   = (unsigned short*)alloc(512 * 256 * 2);
    unsigned short* Wt2   = (unsigned short*)alloc(512 * 256 * 2);
    unsigned short* We2T  = (unsigned short*)alloc(32 * 256 * 2);
    float* P     = (float*)alloc((size_t)N_NODES * 32 * 4);
    int* counts  = (int*)alloc((size_t)N_NODES * 4);
    int* offsets = (int*)alloc((size_t)(N_NODES + 1) * 4);
    int* cur     = (int*)alloc((size_t)N_NODES * 4);
    int* csr     = (int*)alloc((size_t)N_EDGES * 4);
    int* bsum    = (int*)alloc(512 * 4);
    float* sums  = (float*)alloc(N_GRAPHS * HID * 4);

    const int nscan = (N_NODES + 255) / 256; // 391

    hipMemsetAsync(counts, 0, (size_t)N_NODES * 4, stream);
    hipMemsetAsync(sums, 0, N_GRAPHS * HID * 4, stream);

    // weight prep
    k_makeWt<<<dim3(8, 8), 256, 0, stream>>>(W_rel0, W_root0, Wt0, 512);
    k_makeWt<<<dim3(4, 8), 256, 0, stream>>>(W_rel1, W_root1, Wt1, 256);
    k_makeWt<<<dim3(4, 8), 256, 0, stream>>>(W_rel2, W_root2, Wt2, 256);
    k_makeWe2T<<<32, 256, 0, stream>>>(W_edge, We2T);

    // CSR build
    k_hist<<<(N_EDGES + 255) / 256, 256, 0, stream>>>(dst, counts);
    k_scanA<<<nscan, 256, 0, stream>>>(counts, bsum);
    k_scanB<<<1, 256, 0, stream>>>(bsum, nscan);
    k_scanC<<<nscan, 256, 0, stream>>>(counts, bsum, offsets, cur);
    k_fill<<<(N_EDGES + 255) / 256, 256, 0, stream>>>(src, dst, cur, csr);

    const int gemmGrid = ((N_NODES + 127) / 128) * 4; // 782*4 = 3128, %8==0
    // layer 0 (fp32 A, fused conversion)
    k_gemm0<<<gemmGrid, 256, 0, stream>>>(node_feats, Wt0, Yrel, Yroot, N_NODES);
    k_combine<<<(N_NODES + 3) / 4, 256, 0, stream>>>(Yrel, Yroot, offsets, csr, b0, xB);
    // layer 1
    k_gemm<<<gemmGrid, 256, 0, stream>>>(xB, Wt1, Yrel, Yroot, N_NODES, 256);
    k_combine<<<(N_NODES + 3) / 4, 256, 0, stream>>>(Yrel, Yroot, offsets, csr, b1, xA);
    // layer 2
    k_gemm<<<gemmGrid, 256, 0, stream>>>(xA, Wt2, Yrel, Yroot, N_NODES, 256);
    k_combine<<<(N_NODES + 3) / 4, 256, 0, stream>>>(Yrel, Yroot, offsets, csr, b2, xB);

    // edge head -> d_out[0 : 8M)
    float* out_logits = (float*)d_out;
    k_proj<<<(N_NODES / 16 + 3) / 4, 256, 0, stream>>>(xB, We2T, P);
    k_edge_add<<<(N_EDGES + 255) / 256, 256, 0, stream>>>(P, src, dst, b_edge, out_logits);

    // mean pool -> d_out[8M : 8M+16384)
    float* out_embed = (float*)d_out + (size_t)N_EDGES * NREL;
    k_pool_sum<<<(N_NODES + 127) / 128, 256, 0, stream>>>(xB, batch_idx, sums);
    k_pool_final<<<N_GRAPHS, 256, 0, stream>>>(sums, batch_idx, out_embed);
}

// Round 8
// 514.502 us; speedup vs baseline: 1.1774x; 1.0589x over previous
//
#include <hip/hip_runtime.h>

#define N_NODES 100000
#define N_EDGES 500000
#define N_GRAPHS 64
#define IN_DIM 512
#define HID 256
#define NREL 16

using short8 = __attribute__((ext_vector_type(8))) short;
using f32x4  = __attribute__((ext_vector_type(4))) float;

__device__ __forceinline__ unsigned short f2bf(float f) {
    union { float f; unsigned u; } v; v.f = f;
    unsigned u = v.u;
    unsigned r = u + 0x7FFF + ((u >> 16) & 1);
    return (unsigned short)(r >> 16);
}
__device__ __forceinline__ float bf2f(unsigned short h) {
    union { unsigned u; float f; } v; v.u = ((unsigned)h) << 16;
    return v.f;
}

__device__ __forceinline__ void gload_lds16(const unsigned short* g, unsigned short* l) {
    __builtin_amdgcn_global_load_lds(
        (const __attribute__((address_space(1))) void*)(g),
        (__attribute__((address_space(3))) void*)(l), 16, 0, 0);
}
__device__ __forceinline__ void gload_lds16f(const float* g, float* l) {
    __builtin_amdgcn_global_load_lds(
        (const __attribute__((address_space(1))) void*)(g),
        (__attribute__((address_space(3))) void*)(l), 16, 0, 0);
}

// ---------------- weight prep: Wt[n][k] = bf16(n<256 ? Wrel[k][n] : Wroot[k][n-256]) ----------
__global__ void k_makeWt(const float* __restrict__ Wrel, const float* __restrict__ Wroot,
                         unsigned short* __restrict__ Wt, int K) {
    __shared__ float t[64][65];
    int tid = threadIdx.x;
    int tk = blockIdx.x * 64, tn = blockIdx.y * 64;
    const float* Wsrc = (tn < 256) ? Wrel : Wroot;
    int col0 = tn & 255;
    #pragma unroll
    for (int r = 0; r < 16; ++r) {
        int kl = r * 4 + (tid >> 6);
        int nl = tid & 63;
        t[kl][nl] = Wsrc[(size_t)(tk + kl) * 256 + col0 + nl];
    }
    __syncthreads();
    #pragma unroll
    for (int r = 0; r < 16; ++r) {
        int nl = r * 4 + (tid >> 6);
        int kl = tid & 63;
        Wt[(size_t)(tn + nl) * K + tk + kl] = f2bf(t[kl][nl]);
    }
}

// We2T[r][k], r<32, k<256: r<16 -> W_edge[k][r] (src half); r>=16 -> W_edge[256+k][r-16]
__global__ void k_makeWe2T(const float* __restrict__ We, unsigned short* __restrict__ We2T) {
    int idx = blockIdx.x * 256 + threadIdx.x;
    if (idx >= 32 * 256) return;
    int r = idx >> 8, k = idx & 255;
    float v = (r < 16) ? We[k * NREL + r] : We[(256 + k) * NREL + (r - 16)];
    We2T[idx] = f2bf(v);
}

// ---------------- CSR build ----------------
__global__ void k_hist(const int* __restrict__ dstArr, int* __restrict__ counts) {
    int i = blockIdx.x * 256 + threadIdx.x;
    if (i < N_EDGES) atomicAdd(&counts[dstArr[i]], 1);
}

__global__ void k_scanA(const int* __restrict__ counts, int* __restrict__ bsum) {
    __shared__ int ws[4];
    int i = blockIdx.x * 256 + threadIdx.x;
    int v = (i < N_NODES) ? counts[i] : 0;
    for (int o = 32; o; o >>= 1) v += __shfl_down(v, o, 64);
    if ((threadIdx.x & 63) == 0) ws[threadIdx.x >> 6] = v;
    __syncthreads();
    if (threadIdx.x == 0) bsum[blockIdx.x] = ws[0] + ws[1] + ws[2] + ws[3];
}

__global__ void k_scanB(int* __restrict__ bsum, int nb) {
    __shared__ int buf[512];
    int t = threadIdx.x;
    for (int i = t; i < nb; i += 256) buf[i] = bsum[i];
    __syncthreads();
    if (t == 0) { int s = 0; for (int i = 0; i < nb; ++i) { int x = buf[i]; buf[i] = s; s += x; } }
    __syncthreads();
    for (int i = t; i < nb; i += 256) bsum[i] = buf[i];
}

__global__ void k_scanC(const int* __restrict__ counts, const int* __restrict__ bsum,
                        int* __restrict__ offsets, int* __restrict__ cur) {
    __shared__ int ws[4];
    int i = blockIdx.x * 256 + threadIdx.x;
    int lane = threadIdx.x & 63, wid = threadIdx.x >> 6;
    int v = (i < N_NODES) ? counts[i] : 0;
    int x = v;
    for (int o = 1; o < 64; o <<= 1) { int u = __shfl_up(x, o, 64); if (lane >= o) x += u; }
    if (lane == 63) ws[wid] = x;
    __syncthreads();
    if (threadIdx.x == 0) { int s = 0; for (int t = 0; t < 4; ++t) { int tt = ws[t]; ws[t] = s; s += tt; } }
    __syncthreads();
    x += ws[wid];
    x += bsum[blockIdx.x];
    if (i < N_NODES) { offsets[i + 1] = x; cur[i] = x - v; }
    if (i == 0) offsets[0] = 0;
}

__global__ void k_fill(const int* __restrict__ srcArr, const int* __restrict__ dstArr,
                       int* __restrict__ cur, int* __restrict__ csr) {
    int i = blockIdx.x * 256 + threadIdx.x;
    if (i < N_EDGES) {
        int p = atomicAdd(&cur[dstArr[i]], 1);
        csr[p] = srcArr[i];
    }
}

// ---------------- GEMM (bf16 A): [Yrel|Yroot][M x 256] = A[M x K] @ Bt[512 x K]^T ----------
__global__ __launch_bounds__(256) void k_gemm(const unsigned short* __restrict__ A,
                                              const unsigned short* __restrict__ Bt,
                                              unsigned short* __restrict__ Yrel,
                                              unsigned short* __restrict__ Yroot,
                                              int M, int K) {
    __shared__ unsigned short lds[2 * 128 * 64];
    const int tid  = threadIdx.x;
    const int lane = tid & 63;
    const int w    = tid >> 6;
    const int wm   = w >> 1, wn = w & 1;

    int nwg  = gridDim.x;
    int orig = blockIdx.x;
    int q    = nwg >> 3;
    int id   = (orig & 7) * q + (orig >> 3);
    int bm0  = (id >> 2) * 128;
    int bn0  = (id & 3) * 128;

    f32x4 acc[4][4] = {};

    const int nkt = K >> 6;
    for (int kt = 0; kt < nkt; ++kt) {
        int k0 = kt << 6;
        #pragma unroll
        for (int it = 0; it < 4; ++it) {
            int c = (it << 8) + tid;
            int row = c >> 3, kcp = c & 7;
            int kcl = kcp ^ (row & 7);
            int gr = bm0 + row; gr = (gr < M) ? gr : (M - 1);
            gload_lds16(A + (size_t)gr * K + k0 + kcl * 8,
                        &lds[(size_t)((it << 8) + (w << 6)) * 8]);
        }
        #pragma unroll
        for (int it = 0; it < 4; ++it) {
            int c = (it << 8) + tid;
            int row = c >> 3, kcp = c & 7;
            int kcl = kcp ^ (row & 7);
            gload_lds16(Bt + (size_t)(bn0 + row) * K + k0 + kcl * 8,
                        &lds[128 * 64 + (size_t)((it << 8) + (w << 6)) * 8]);
        }
        __syncthreads();
        #pragma unroll
        for (int kk = 0; kk < 2; ++kk) {
            short8 af[4], bfr[4];
            #pragma unroll
            for (int m = 0; m < 4; ++m) {
                int row = wm * 64 + m * 16 + (lane & 15);
                int g = ((kk << 2) + (lane >> 4)) ^ (row & 7);
                af[m] = *(const short8*)&lds[row * 64 + g * 8];
            }
            #pragma unroll
            for (int n = 0; n < 4; ++n) {
                int row = wn * 64 + n * 16 + (lane & 15);
                int g = ((kk << 2) + (lane >> 4)) ^ (row & 7);
                bfr[n] = *(const short8*)&lds[128 * 64 + row * 64 + g * 8];
            }
            #pragma unroll
            for (int m = 0; m < 4; ++m)
                #pragma unroll
                for (int n = 0; n < 4; ++n)
                    acc[m][n] = __builtin_amdgcn_mfma_f32_16x16x32_bf16(af[m], bfr[n], acc[m][n], 0, 0, 0);
        }
        __syncthreads();
    }
    unsigned short* Cout = (bn0 < 256) ? Yrel : Yroot;
    int cb = bn0 & 255;
    #pragma unroll
    for (int m = 0; m < 4; ++m) {
        int row0 = bm0 + wm * 64 + m * 16 + ((lane >> 4) << 2);
        #pragma unroll
        for (int n = 0; n < 4; ++n) {
            int col = cb + wn * 64 + n * 16 + (lane & 15);
            #pragma unroll
            for (int i = 0; i < 4; ++i) {
                int r = row0 + i;
                if (r < M) Cout[(size_t)r * 256 + col] = f2bf(acc[m][n][i]);
            }
        }
    }
}

// ---------------- GEMM L0 (fp32 A via async global_load_lds, cvt on fragment read) ----------
// Same proven 2-barrier structure as k_gemm; A tile is [128][64] fp32 (32 KB) staged by DMA,
// granule (16B = 4 floats) XOR swizzle: LDS pos gp holds global granule gp^(row&15).
__global__ __launch_bounds__(256) void k_gemm0(const float* __restrict__ A,
                                               const unsigned short* __restrict__ Bt,
                                               unsigned short* __restrict__ Yrel,
                                               unsigned short* __restrict__ Yroot,
                                               int M) {
    constexpr int K = 512;
    __shared__ float ldsA[128 * 64];            // 32 KB
    __shared__ unsigned short ldsB[128 * 64];   // 16 KB
    const int tid  = threadIdx.x;
    const int lane = tid & 63;
    const int w    = tid >> 6;
    const int wm   = w >> 1, wn = w & 1;

    int nwg  = gridDim.x;
    int orig = blockIdx.x;
    int q    = nwg >> 3;
    int id   = (orig & 7) * q + (orig >> 3);
    int bm0  = (id >> 2) * 128;
    int bn0  = (id & 3) * 128;

    f32x4 acc[4][4] = {};

    const int nkt = K >> 6;
    for (int kt = 0; kt < nkt; ++kt) {
        int k0 = kt << 6;
        // stage A fp32 tile: 2048 granules of 16B, linear LDS dest, swizzled global source
        #pragma unroll
        for (int it = 0; it < 8; ++it) {
            int gi = (it << 8) + tid;          // granule id
            int row = gi >> 4, gp = gi & 15;
            int gs = gp ^ (row & 15);
            int gr = bm0 + row; gr = (gr < M) ? gr : (M - 1);
            gload_lds16f(A + (size_t)gr * K + k0 + gs * 4,
                         &ldsA[(size_t)((it << 8) + (w << 6)) * 4]);
        }
        // stage B bf16 tile (identical to k_gemm)
        #pragma unroll
        for (int it = 0; it < 4; ++it) {
            int c = (it << 8) + tid;
            int row = c >> 3, kcp = c & 7;
            int kcl = kcp ^ (row & 7);
            gload_lds16(Bt + (size_t)(bn0 + row) * K + k0 + kcl * 8,
                        &ldsB[(size_t)((it << 8) + (w << 6)) * 8]);
        }
        __syncthreads();
        #pragma unroll
        for (int kk = 0; kk < 2; ++kk) {
            short8 af[4], bfr[4];
            #pragma unroll
            for (int m = 0; m < 4; ++m) {
                int row = wm * 64 + m * 16 + (lane & 15);
                int c = (kk << 2) + (lane >> 4);           // 8-float chunk index
                int g0 = (2 * c) ^ (row & 15);
                int g1 = (2 * c + 1) ^ (row & 15);
                f32x4 fa = *(const f32x4*)&ldsA[row * 64 + g0 * 4];
                f32x4 fb = *(const f32x4*)&ldsA[row * 64 + g1 * 4];
                short8 v;
                v[0] = (short)f2bf(fa[0]); v[1] = (short)f2bf(fa[1]);
                v[2] = (short)f2bf(fa[2]); v[3] = (short)f2bf(fa[3]);
                v[4] = (short)f2bf(fb[0]); v[5] = (short)f2bf(fb[1]);
                v[6] = (short)f2bf(fb[2]); v[7] = (short)f2bf(fb[3]);
                af[m] = v;
            }
            #pragma unroll
            for (int n = 0; n < 4; ++n) {
                int row = wn * 64 + n * 16 + (lane & 15);
                int g = ((kk << 2) + (lane >> 4)) ^ (row & 7);
                bfr[n] = *(const short8*)&ldsB[row * 64 + g * 8];
            }
            #pragma unroll
            for (int m = 0; m < 4; ++m)
                #pragma unroll
                for (int n = 0; n < 4; ++n)
                    acc[m][n] = __builtin_amdgcn_mfma_f32_16x16x32_bf16(af[m], bfr[n], acc[m][n], 0, 0, 0);
        }
        __syncthreads();
    }
    unsigned short* Cout = (bn0 < 256) ? Yrel : Yroot;
    int cb = bn0 & 255;
    #pragma unroll
    for (int m = 0; m < 4; ++m) {
        int row0 = bm0 + wm * 64 + m * 16 + ((lane >> 4) << 2);
        #pragma unroll
        for (int n = 0; n < 4; ++n) {
            int col = cb + wn * 64 + n * 16 + (lane & 15);
            #pragma unroll
            for (int i = 0; i < 4; ++i) {
                int r = row0 + i;
                if (r < M) Cout[(size_t)r * 256 + col] = f2bf(acc[m][n][i]);
            }
        }
    }
}

// ---------------- fused aggregate + root + bias + ReLU -> bf16 (4-way ILP) ----------------
__device__ __forceinline__ void acc4(float4& a, ushort4 v) {
    a.x += bf2f(v.x); a.y += bf2f(v.y); a.z += bf2f(v.z); a.w += bf2f(v.w);
}

__global__ void k_combine(const unsigned short* __restrict__ yrel,
                          const unsigned short* __restrict__ yroot,
                          const int* __restrict__ offs,
                          const int* __restrict__ csr, const float* __restrict__ bias,
                          unsigned short* __restrict__ xout) {
    int node = blockIdx.x * 4 + (threadIdx.x >> 6);
    if (node >= N_NODES) return;
    int lane = threadIdx.x & 63;
    int d = lane * 4;
    int j0 = offs[node], j1 = offs[node + 1];
    float4 a0 = {0,0,0,0}, a1 = {0,0,0,0}, a2 = {0,0,0,0}, a3 = {0,0,0,0};
    int j = j0;
    for (; j + 4 <= j1; j += 4) {
        int s0 = csr[j], s1 = csr[j + 1], s2 = csr[j + 2], s3 = csr[j + 3];
        ushort4 v0 = *(const ushort4*)(yrel + (size_t)s0 * 256 + d);
        ushort4 v1 = *(const ushort4*)(yrel + (size_t)s1 * 256 + d);
        ushort4 v2 = *(const ushort4*)(yrel + (size_t)s2 * 256 + d);
        ushort4 v3 = *(const ushort4*)(yrel + (size_t)s3 * 256 + d);
        acc4(a0, v0); acc4(a1, v1); acc4(a2, v2); acc4(a3, v3);
    }
    for (; j < j1; ++j) {
        int s = csr[j];
        acc4(a0, *(const ushort4*)(yrel + (size_t)s * 256 + d));
    }
    a0.x += a1.x + a2.x + a3.x;
    a0.y += a1.y + a2.y + a3.y;
    a0.z += a1.z + a2.z + a3.z;
    a0.w += a1.w + a2.w + a3.w;
    ushort4 rr = *(const ushort4*)(yroot + (size_t)node * 256 + d);
    float4 bb = *(const float4*)(bias + d);
    ushort4 pk;
    pk.x = f2bf(fmaxf(a0.x + bf2f(rr.x) + bb.x, 0.f));
    pk.y = f2bf(fmaxf(a0.y + bf2f(rr.y) + bb.y, 0.f));
    pk.z = f2bf(fmaxf(a0.z + bf2f(rr.z) + bb.z, 0.f));
    pk.w = f2bf(fmaxf(a0.w + bf2f(rr.w) + bb.w, 0.f));
    *(ushort4*)(xout + (size_t)node * HID + d) = pk;
}

// ---------------- edge head, stage 1: P[N x 32] = x3 @ We2T^T (fp32 out) ----------------
__global__ void k_proj(const unsigned short* __restrict__ x,
                       const unsigned short* __restrict__ We2T,
                       float* __restrict__ P) {
    int lane = threadIdx.x & 63;
    int g = blockIdx.x * 4 + (threadIdx.x >> 6);
    if (g * 16 >= N_NODES) return;
    int n0 = g * 16;
    short8 bfr[2][8];
    #pragma unroll
    for (int cg = 0; cg < 2; ++cg)
        #pragma unroll
        for (int ks = 0; ks < 8; ++ks)
            bfr[cg][ks] = *(const short8*)&We2T[(size_t)(cg * 16 + (lane & 15)) * 256 + ks * 32 + ((lane >> 4) << 3)];
    f32x4 acc[2] = {};
    const size_t rb = (size_t)(n0 + (lane & 15)) * 256 + ((lane >> 4) << 3);
    #pragma unroll
    for (int ks = 0; ks < 8; ++ks) {
        short8 af = *(const short8*)&x[rb + ks * 32];
        acc[0] = __builtin_amdgcn_mfma_f32_16x16x32_bf16(af, bfr[0][ks], acc[0], 0, 0, 0);
        acc[1] = __builtin_amdgcn_mfma_f32_16x16x32_bf16(af, bfr[1][ks], acc[1], 0, 0, 0);
    }
    #pragma unroll
    for (int cg = 0; cg < 2; ++cg) {
        #pragma unroll
        for (int i = 0; i < 4; ++i) {
            int n = n0 + ((lane >> 4) << 2) + i;
            P[(size_t)n * 32 + cg * 16 + (lane & 15)] = acc[cg][i];
        }
    }
}

// ---------------- edge head, stage 2: out[e] = P[src][0:16] + P[dst][16:32] + b ----------
__global__ void k_edge_add(const float* __restrict__ P,
                           const int* __restrict__ srcArr, const int* __restrict__ dstArr,
                           const float* __restrict__ b_edge, float* __restrict__ out) {
    int e = blockIdx.x * 256 + threadIdx.x;
    if (e >= N_EDGES) return;
    int s = srcArr[e], d = dstArr[e];
    const float4* ps = (const float4*)(P + (size_t)s * 32);
    const float4* pd = (const float4*)(P + (size_t)d * 32 + 16);
    const float4* bb = (const float4*)b_edge;
    float4* po = (float4*)(out + (size_t)e * 16);
    #pragma unroll
    for (int i = 0; i < 4; ++i) {
        float4 a = ps[i], b = pd[i], c = bb[i];
        float4 rr;
        rr.x = a.x + b.x + c.x; rr.y = a.y + b.y + c.y;
        rr.z = a.z + b.z + c.z; rr.w = a.w + b.w + c.w;
        po[i] = rr;
    }
}

// ---------------- mean pool ----------------
__global__ void k_pool_sum(const unsigned short* __restrict__ x, const int* __restrict__ batch,
                           float* __restrict__ sums) {
    const int CH = 32;
    int w = threadIdx.x >> 6, lane = threadIdx.x & 63;
    int n0 = blockIdx.x * (4 * CH) + w * CH;
    if (n0 >= N_NODES) return;
    int n1 = n0 + CH; if (n1 > N_NODES) n1 = N_NODES;
    int d = lane * 4;
    float a0 = 0.f, a1 = 0.f, a2 = 0.f, a3 = 0.f;
    int gcur = batch[n0];
    for (int n = n0; n < n1; ++n) {
        int g = batch[n];
        if (g != gcur) {
            float* p = &sums[gcur * HID + d];
            atomicAdd(p + 0, a0); atomicAdd(p + 1, a1);
            atomicAdd(p + 2, a2); atomicAdd(p + 3, a3);
            a0 = a1 = a2 = a3 = 0.f; gcur = g;
        }
        ushort4 v = *(const ushort4*)&x[(size_t)n * HID + d];
        a0 += bf2f(v.x); a1 += bf2f(v.y); a2 += bf2f(v.z); a3 += bf2f(v.w);
    }
    float* p = &sums[gcur * HID + d];
    atomicAdd(p + 0, a0); atomicAdd(p + 1, a1);
    atomicAdd(p + 2, a2); atomicAdd(p + 3, a3);
}

__device__ __forceinline__ int lowerBound(const int* a, int n, int key) {
    int lo = 0, hi = n;
    while (lo < hi) { int mid = (lo + hi) >> 1; if (a[mid] < key) lo = mid + 1; else hi = mid; }
    return lo;
}

__global__ void k_pool_final(const float* __restrict__ sums, const int* __restrict__ batch,
                             float* __restrict__ out) {
    int g = blockIdx.x, d = threadIdx.x;
    int lo = lowerBound(batch, N_NODES, g);
    int hi = lowerBound(batch, N_NODES, g + 1);
    float cnt = (float)(hi - lo);
    out[(size_t)g * HID + d] = sums[g * HID + d] / fmaxf(cnt, 1.0f);
}

// ---------------- launcher ----------------
extern "C" void kernel_launch(void* const* d_in, const int* in_sizes, int n_in,
                              void* d_out, int out_size, void* d_ws, size_t ws_size,
                              hipStream_t stream) {
    const float* node_feats = (const float*)d_in[0];
    const int*   edge_index = (const int*)d_in[1];
    const int*   batch_idx  = (const int*)d_in[2];
    const float* W_rel0  = (const float*)d_in[3];
    const float* W_root0 = (const float*)d_in[4];
    const float* b0      = (const float*)d_in[5];
    const float* W_rel1  = (const float*)d_in[6];
    const float* W_root1 = (const float*)d_in[7];
    const float* b1      = (const float*)d_in[8];
    const float* W_rel2  = (const float*)d_in[9];
    const float* W_root2 = (const float*)d_in[10];
    const float* b2      = (const float*)d_in[11];
    const float* W_edge  = (const float*)d_in[12];
    const float* b_edge  = (const float*)d_in[13];

    const int* src = edge_index;
    const int* dst = edge_index + N_EDGES;

    char* ws = (char*)d_ws;
    size_t off = 0;
    auto alloc = [&](size_t bytes) -> char* {
        off = (off + 255) & ~(size_t)255;
        char* p = ws + off;
        off += bytes;
        return p;
    };
    unsigned short* xA    = (unsigned short*)alloc((size_t)N_NODES * HID * 2);  // x2
    unsigned short* xB    = (unsigned short*)alloc((size_t)N_NODES * HID * 2);  // x1 / x3
    unsigned short* Yrel  = (unsigned short*)alloc((size_t)N_NODES * HID * 2);
    unsigned short* Yroot = (unsigned short*)alloc((size_t)N_NODES * HID * 2);
    unsigned short* Wt0   = (unsigned short*)alloc(512 * 512 * 2);
    unsigned short* Wt1   = (unsigned short*)alloc(512 * 256 * 2);
    unsigned short* Wt2   = (unsigned short*)alloc(512 * 256 * 2);
    unsigned short* We2T  = (unsigned short*)alloc(32 * 256 * 2);
    float* P     = (float*)alloc((size_t)N_NODES * 32 * 4);
    int* counts  = (int*)alloc((size_t)N_NODES * 4);
    int* offsets = (int*)alloc((size_t)(N_NODES + 1) * 4);
    int* cur     = (int*)alloc((size_t)N_NODES * 4);
    int* csr     = (int*)alloc((size_t)N_EDGES * 4);
    int* bsum    = (int*)alloc(512 * 4);
    float* sums  = (float*)alloc(N_GRAPHS * HID * 4);

    const int nscan = (N_NODES + 255) / 256; // 391

    hipMemsetAsync(counts, 0, (size_t)N_NODES * 4, stream);
    hipMemsetAsync(sums, 0, N_GRAPHS * HID * 4, stream);

    // weight prep
    k_makeWt<<<dim3(8, 8), 256, 0, stream>>>(W_rel0, W_root0, Wt0, 512);
    k_makeWt<<<dim3(4, 8), 256, 0, stream>>>(W_rel1, W_root1, Wt1, 256);
    k_makeWt<<<dim3(4, 8), 256, 0, stream>>>(W_rel2, W_root2, Wt2, 256);
    k_makeWe2T<<<32, 256, 0, stream>>>(W_edge, We2T);

    // CSR build
    k_hist<<<(N_EDGES + 255) / 256, 256, 0, stream>>>(dst, counts);
    k_scanA<<<nscan, 256, 0, stream>>>(counts, bsum);
    k_scanB<<<1, 256, 0, stream>>>(bsum, nscan);
    k_scanC<<<nscan, 256, 0, stream>>>(counts, bsum, offsets, cur);
    k_fill<<<(N_EDGES + 255) / 256, 256, 0, stream>>>(src, dst, cur, csr);

    const int gemmGrid = ((N_NODES + 127) / 128) * 4; // 782*4 = 3128, %8==0
    // layer 0 (fp32 A via async DMA staging, cvt on read)
    k_gemm0<<<gemmGrid, 256, 0, stream>>>(node_feats, Wt0, Yrel, Yroot, N_NODES);
    k_combine<<<(N_NODES + 3) / 4, 256, 0, stream>>>(Yrel, Yroot, offsets, csr, b0, xB);
    // layer 1
    k_gemm<<<gemmGrid, 256, 0, stream>>>(xB, Wt1, Yrel, Yroot, N_NODES, 256);
    k_combine<<<(N_NODES + 3) / 4, 256, 0, stream>>>(Yrel, Yroot, offsets, csr, b1, xA);
    // layer 2
    k_gemm<<<gemmGrid, 256, 0, stream>>>(xA, Wt2, Yrel, Yroot, N_NODES, 256);
    k_combine<<<(N_NODES + 3) / 4, 256, 0, stream>>>(Yrel, Yroot, offsets, csr, b2, xB);

    // edge head -> d_out[0 : 8M)
    float* out_logits = (float*)d_out;
    k_proj<<<(N_NODES / 16 + 3) / 4, 256, 0, stream>>>(xB, We2T, P);
    k_edge_add<<<(N_EDGES + 255) / 256, 256, 0, stream>>>(P, src, dst, b_edge, out_logits);

    // mean pool -> d_out[8M : 8M+16384)
    float* out_embed = (float*)d_out + (size_t)N_EDGES * NREL;
    k_pool_sum<<<(N_NODES + 127) / 128, 256, 0, stream>>>(xB, batch_idx, sums);
    k_pool_final<<<N_GRAPHS, 256, 0, stream>>>(sums, batch_idx, out_embed);
}

// Round 9
// 513.147 us; speedup vs baseline: 1.1805x; 1.0026x over previous
//
#include <hip/hip_runtime.h>

#define N_NODES 100000
#define N_EDGES 500000
#define N_GRAPHS 64
#define IN_DIM 512
#define HID 256
#define NREL 16

using short8 = __attribute__((ext_vector_type(8))) short;
using f32x4  = __attribute__((ext_vector_type(4))) float;

__device__ __forceinline__ unsigned short f2bf(float f) {
    union { float f; unsigned u; } v; v.f = f;
    unsigned u = v.u;
    unsigned r = u + 0x7FFF + ((u >> 16) & 1);
    return (unsigned short)(r >> 16);
}
__device__ __forceinline__ float bf2f(unsigned short h) {
    union { unsigned u; float f; } v; v.u = ((unsigned)h) << 16;
    return v.f;
}
// packed fp32->bf16 RNE (native, gfx950): lo -> bits[15:0], hi -> bits[31:16]
__device__ __forceinline__ unsigned cvtpk(float lo, float hi) {
    unsigned r;
    asm("v_cvt_pk_bf16_f32 %0, %1, %2" : "=v"(r) : "v"(lo), "v"(hi));
    return r;
}

__device__ __forceinline__ void gload_lds16(const unsigned short* g, unsigned short* l) {
    __builtin_amdgcn_global_load_lds(
        (const __attribute__((address_space(1))) void*)(g),
        (__attribute__((address_space(3))) void*)(l), 16, 0, 0);
}
__device__ __forceinline__ void gload_lds16f(const float* g, float* l) {
    __builtin_amdgcn_global_load_lds(
        (const __attribute__((address_space(1))) void*)(g),
        (__attribute__((address_space(3))) void*)(l), 16, 0, 0);
}

// ---------------- weight prep: Wt[n][k] = bf16(n<256 ? Wrel[k][n] : Wroot[k][n-256]) ----------
__global__ void k_makeWt(const float* __restrict__ Wrel, const float* __restrict__ Wroot,
                         unsigned short* __restrict__ Wt, int K) {
    __shared__ float t[64][65];
    int tid = threadIdx.x;
    int tk = blockIdx.x * 64, tn = blockIdx.y * 64;
    const float* Wsrc = (tn < 256) ? Wrel : Wroot;
    int col0 = tn & 255;
    #pragma unroll
    for (int r = 0; r < 16; ++r) {
        int kl = r * 4 + (tid >> 6);
        int nl = tid & 63;
        t[kl][nl] = Wsrc[(size_t)(tk + kl) * 256 + col0 + nl];
    }
    __syncthreads();
    #pragma unroll
    for (int r = 0; r < 16; ++r) {
        int nl = r * 4 + (tid >> 6);
        int kl = tid & 63;
        Wt[(size_t)(tn + nl) * K + tk + kl] = f2bf(t[kl][nl]);
    }
}

// We2T[r][k], r<32, k<256: r<16 -> W_edge[k][r] (src half); r>=16 -> W_edge[256+k][r-16]
__global__ void k_makeWe2T(const float* __restrict__ We, unsigned short* __restrict__ We2T) {
    int idx = blockIdx.x * 256 + threadIdx.x;
    if (idx >= 32 * 256) return;
    int r = idx >> 8, k = idx & 255;
    float v = (r < 16) ? We[k * NREL + r] : We[(256 + k) * NREL + (r - 16)];
    We2T[idx] = f2bf(v);
}

// ---------------- CSR build ----------------
__global__ void k_hist(const int* __restrict__ dstArr, int* __restrict__ counts) {
    int i = blockIdx.x * 256 + threadIdx.x;
    if (i < N_EDGES) atomicAdd(&counts[dstArr[i]], 1);
}

__global__ void k_scanA(const int* __restrict__ counts, int* __restrict__ bsum) {
    __shared__ int ws[4];
    int i = blockIdx.x * 256 + threadIdx.x;
    int v = (i < N_NODES) ? counts[i] : 0;
    for (int o = 32; o; o >>= 1) v += __shfl_down(v, o, 64);
    if ((threadIdx.x & 63) == 0) ws[threadIdx.x >> 6] = v;
    __syncthreads();
    if (threadIdx.x == 0) bsum[blockIdx.x] = ws[0] + ws[1] + ws[2] + ws[3];
}

__global__ void k_scanB(int* __restrict__ bsum, int nb) {
    __shared__ int buf[512];
    int t = threadIdx.x;
    for (int i = t; i < nb; i += 256) buf[i] = bsum[i];
    __syncthreads();
    if (t == 0) { int s = 0; for (int i = 0; i < nb; ++i) { int x = buf[i]; buf[i] = s; s += x; } }
    __syncthreads();
    for (int i = t; i < nb; i += 256) bsum[i] = buf[i];
}

__global__ void k_scanC(const int* __restrict__ counts, const int* __restrict__ bsum,
                        int* __restrict__ offsets, int* __restrict__ cur) {
    __shared__ int ws[4];
    int i = blockIdx.x * 256 + threadIdx.x;
    int lane = threadIdx.x & 63, wid = threadIdx.x >> 6;
    int v = (i < N_NODES) ? counts[i] : 0;
    int x = v;
    for (int o = 1; o < 64; o <<= 1) { int u = __shfl_up(x, o, 64); if (lane >= o) x += u; }
    if (lane == 63) ws[wid] = x;
    __syncthreads();
    if (threadIdx.x == 0) { int s = 0; for (int t = 0; t < 4; ++t) { int tt = ws[t]; ws[t] = s; s += tt; } }
    __syncthreads();
    x += ws[wid];
    x += bsum[blockIdx.x];
    if (i < N_NODES) { offsets[i + 1] = x; cur[i] = x - v; }
    if (i == 0) offsets[0] = 0;
}

__global__ void k_fill(const int* __restrict__ srcArr, const int* __restrict__ dstArr,
                       int* __restrict__ cur, int* __restrict__ csr) {
    int i = blockIdx.x * 256 + threadIdx.x;
    if (i < N_EDGES) {
        int p = atomicAdd(&cur[dstArr[i]], 1);
        csr[p] = srcArr[i];
    }
}

// ---------------- GEMM (bf16 A): [Yrel|Yroot][M x 256] = A[M x K] @ Bt[512 x K]^T ----------
__global__ __launch_bounds__(256) void k_gemm(const unsigned short* __restrict__ A,
                                              const unsigned short* __restrict__ Bt,
                                              unsigned short* __restrict__ Yrel,
                                              unsigned short* __restrict__ Yroot,
                                              int M, int K) {
    __shared__ unsigned short lds[2 * 128 * 64];
    const int tid  = threadIdx.x;
    const int lane = tid & 63;
    const int w    = tid >> 6;
    const int wm   = w >> 1, wn = w & 1;

    int nwg  = gridDim.x;
    int orig = blockIdx.x;
    int q    = nwg >> 3;
    int id   = (orig & 7) * q + (orig >> 3);
    int bm0  = (id >> 2) * 128;
    int bn0  = (id & 3) * 128;

    f32x4 acc[4][4] = {};

    const int nkt = K >> 6;
    for (int kt = 0; kt < nkt; ++kt) {
        int k0 = kt << 6;
        #pragma unroll
        for (int it = 0; it < 4; ++it) {
            int c = (it << 8) + tid;
            int row = c >> 3, kcp = c & 7;
            int kcl = kcp ^ (row & 7);
            int gr = bm0 + row; gr = (gr < M) ? gr : (M - 1);
            gload_lds16(A + (size_t)gr * K + k0 + kcl * 8,
                        &lds[(size_t)((it << 8) + (w << 6)) * 8]);
        }
        #pragma unroll
        for (int it = 0; it < 4; ++it) {
            int c = (it << 8) + tid;
            int row = c >> 3, kcp = c & 7;
            int kcl = kcp ^ (row & 7);
            gload_lds16(Bt + (size_t)(bn0 + row) * K + k0 + kcl * 8,
                        &lds[128 * 64 + (size_t)((it << 8) + (w << 6)) * 8]);
        }
        __syncthreads();
        #pragma unroll
        for (int kk = 0; kk < 2; ++kk) {
            short8 af[4], bfr[4];
            #pragma unroll
            for (int m = 0; m < 4; ++m) {
                int row = wm * 64 + m * 16 + (lane & 15);
                int g = ((kk << 2) + (lane >> 4)) ^ (row & 7);
                af[m] = *(const short8*)&lds[row * 64 + g * 8];
            }
            #pragma unroll
            for (int n = 0; n < 4; ++n) {
                int row = wn * 64 + n * 16 + (lane & 15);
                int g = ((kk << 2) + (lane >> 4)) ^ (row & 7);
                bfr[n] = *(const short8*)&lds[128 * 64 + row * 64 + g * 8];
            }
            #pragma unroll
            for (int m = 0; m < 4; ++m)
                #pragma unroll
                for (int n = 0; n < 4; ++n)
                    acc[m][n] = __builtin_amdgcn_mfma_f32_16x16x32_bf16(af[m], bfr[n], acc[m][n], 0, 0, 0);
        }
        __syncthreads();
    }
    unsigned short* Cout = (bn0 < 256) ? Yrel : Yroot;
    int cb = bn0 & 255;
    #pragma unroll
    for (int m = 0; m < 4; ++m) {
        int row0 = bm0 + wm * 64 + m * 16 + ((lane >> 4) << 2);
        #pragma unroll
        for (int n = 0; n < 4; ++n) {
            int col = cb + wn * 64 + n * 16 + (lane & 15);
            #pragma unroll
            for (int i = 0; i < 4; ++i) {
                int r = row0 + i;
                if (r < M) Cout[(size_t)r * 256 + col] = f2bf(acc[m][n][i]);
            }
        }
    }
}

// ---------------- GEMM L0 (fp32 A via async global_load_lds, cvt_pk on fragment read) -------
__global__ __launch_bounds__(256) void k_gemm0(const float* __restrict__ A,
                                               const unsigned short* __restrict__ Bt,
                                               unsigned short* __restrict__ Yrel,
                                               unsigned short* __restrict__ Yroot,
                                               int M) {
    constexpr int K = 512;
    __shared__ float ldsA[128 * 64];            // 32 KB
    __shared__ unsigned short ldsB[128 * 64];   // 16 KB
    const int tid  = threadIdx.x;
    const int lane = tid & 63;
    const int w    = tid >> 6;
    const int wm   = w >> 1, wn = w & 1;

    int nwg  = gridDim.x;
    int orig = blockIdx.x;
    int q    = nwg >> 3;
    int id   = (orig & 7) * q + (orig >> 3);
    int bm0  = (id >> 2) * 128;
    int bn0  = (id & 3) * 128;

    f32x4 acc[4][4] = {};

    const int nkt = K >> 6;
    for (int kt = 0; kt < nkt; ++kt) {
        int k0 = kt << 6;
        // stage A fp32 tile: 2048 granules of 16B, linear LDS dest, swizzled global source
        #pragma unroll
        for (int it = 0; it < 8; ++it) {
            int gi = (it << 8) + tid;          // granule id
            int row = gi >> 4, gp = gi & 15;
            int gs = gp ^ (row & 15);
            int gr = bm0 + row; gr = (gr < M) ? gr : (M - 1);
            gload_lds16f(A + (size_t)gr * K + k0 + gs * 4,
                         &ldsA[(size_t)((it << 8) + (w << 6)) * 4]);
        }
        // stage B bf16 tile (identical to k_gemm)
        #pragma unroll
        for (int it = 0; it < 4; ++it) {
            int c = (it << 8) + tid;
            int row = c >> 3, kcp = c & 7;
            int kcl = kcp ^ (row & 7);
            gload_lds16(Bt + (size_t)(bn0 + row) * K + k0 + kcl * 8,
                        &ldsB[(size_t)((it << 8) + (w << 6)) * 8]);
        }
        __syncthreads();
        #pragma unroll
        for (int kk = 0; kk < 2; ++kk) {
            short8 af[4], bfr[4];
            #pragma unroll
            for (int m = 0; m < 4; ++m) {
                int row = wm * 64 + m * 16 + (lane & 15);
                int c = (kk << 2) + (lane >> 4);           // 8-float chunk index
                int g0 = (2 * c) ^ (row & 15);
                int g1 = (2 * c + 1) ^ (row & 15);
                f32x4 fa = *(const f32x4*)&ldsA[row * 64 + g0 * 4];
                f32x4 fb = *(const f32x4*)&ldsA[row * 64 + g1 * 4];
                union { short8 s8; unsigned u[4]; } vv;
                vv.u[0] = cvtpk(fa[0], fa[1]);
                vv.u[1] = cvtpk(fa[2], fa[3]);
                vv.u[2] = cvtpk(fb[0], fb[1]);
                vv.u[3] = cvtpk(fb[2], fb[3]);
                af[m] = vv.s8;
            }
            #pragma unroll
            for (int n = 0; n < 4; ++n) {
                int row = wn * 64 + n * 16 + (lane & 15);
                int g = ((kk << 2) + (lane >> 4)) ^ (row & 7);
                bfr[n] = *(const short8*)&ldsB[row * 64 + g * 8];
            }
            #pragma unroll
            for (int m = 0; m < 4; ++m)
                #pragma unroll
                for (int n = 0; n < 4; ++n)
                    acc[m][n] = __builtin_amdgcn_mfma_f32_16x16x32_bf16(af[m], bfr[n], acc[m][n], 0, 0, 0);
        }
        __syncthreads();
    }
    unsigned short* Cout = (bn0 < 256) ? Yrel : Yroot;
    int cb = bn0 & 255;
    #pragma unroll
    for (int m = 0; m < 4; ++m) {
        int row0 = bm0 + wm * 64 + m * 16 + ((lane >> 4) << 2);
        #pragma unroll
        for (int n = 0; n < 4; ++n) {
            int col = cb + wn * 64 + n * 16 + (lane & 15);
            #pragma unroll
            for (int i = 0; i < 4; ++i) {
                int r = row0 + i;
                if (r < M) Cout[(size_t)r * 256 + col] = f2bf(acc[m][n][i]);
            }
        }
    }
}

// ---------------- fused aggregate + root + bias + ReLU -> bf16 (4-way ILP) ----------------
__device__ __forceinline__ void acc4(float4& a, ushort4 v) {
    a.x += bf2f(v.x); a.y += bf2f(v.y); a.z += bf2f(v.z); a.w += bf2f(v.w);
}

__global__ void k_combine(const unsigned short* __restrict__ yrel,
                          const unsigned short* __restrict__ yroot,
                          const int* __restrict__ offs,
                          const int* __restrict__ csr, const float* __restrict__ bias,
                          unsigned short* __restrict__ xout) {
    int node = blockIdx.x * 4 + (threadIdx.x >> 6);
    if (node >= N_NODES) return;
    int lane = threadIdx.x & 63;
    int d = lane * 4;
    int j0 = offs[node], j1 = offs[node + 1];
    float4 a0 = {0,0,0,0}, a1 = {0,0,0,0}, a2 = {0,0,0,0}, a3 = {0,0,0,0};
    int j = j0;
    for (; j + 4 <= j1; j += 4) {
        int s0 = csr[j], s1 = csr[j + 1], s2 = csr[j + 2], s3 = csr[j + 3];
        ushort4 v0 = *(const ushort4*)(yrel + (size_t)s0 * 256 + d);
        ushort4 v1 = *(const ushort4*)(yrel + (size_t)s1 * 256 + d);
        ushort4 v2 = *(const ushort4*)(yrel + (size_t)s2 * 256 + d);
        ushort4 v3 = *(const ushort4*)(yrel + (size_t)s3 * 256 + d);
        acc4(a0, v0); acc4(a1, v1); acc4(a2, v2); acc4(a3, v3);
    }
    for (; j < j1; ++j) {
        int s = csr[j];
        acc4(a0, *(const ushort4*)(yrel + (size_t)s * 256 + d));
    }
    a0.x += a1.x + a2.x + a3.x;
    a0.y += a1.y + a2.y + a3.y;
    a0.z += a1.z + a2.z + a3.z;
    a0.w += a1.w + a2.w + a3.w;
    ushort4 rr = *(const ushort4*)(yroot + (size_t)node * 256 + d);
    float4 bb = *(const float4*)(bias + d);
    ushort4 pk;
    pk.x = f2bf(fmaxf(a0.x + bf2f(rr.x) + bb.x, 0.f));
    pk.y = f2bf(fmaxf(a0.y + bf2f(rr.y) + bb.y, 0.f));
    pk.z = f2bf(fmaxf(a0.z + bf2f(rr.z) + bb.z, 0.f));
    pk.w = f2bf(fmaxf(a0.w + bf2f(rr.w) + bb.w, 0.f));
    *(ushort4*)(xout + (size_t)node * HID + d) = pk;
}

// ---------------- edge head, stage 1: P[N x 32] = x3 @ We2T^T (fp32 out) ----------------
__global__ void k_proj(const unsigned short* __restrict__ x,
                       const unsigned short* __restrict__ We2T,
                       float* __restrict__ P) {
    int lane = threadIdx.x & 63;
    int g = blockIdx.x * 4 + (threadIdx.x >> 6);
    if (g * 16 >= N_NODES) return;
    int n0 = g * 16;
    short8 bfr[2][8];
    #pragma unroll
    for (int cg = 0; cg < 2; ++cg)
        #pragma unroll
        for (int ks = 0; ks < 8; ++ks)
            bfr[cg][ks] = *(const short8*)&We2T[(size_t)(cg * 16 + (lane & 15)) * 256 + ks * 32 + ((lane >> 4) << 3)];
    f32x4 acc[2] = {};
    const size_t rb = (size_t)(n0 + (lane & 15)) * 256 + ((lane >> 4) << 3);
    #pragma unroll
    for (int ks = 0; ks < 8; ++ks) {
        short8 af = *(const short8*)&x[rb + ks * 32];
        acc[0] = __builtin_amdgcn_mfma_f32_16x16x32_bf16(af, bfr[0][ks], acc[0], 0, 0, 0);
        acc[1] = __builtin_amdgcn_mfma_f32_16x16x32_bf16(af, bfr[1][ks], acc[1], 0, 0, 0);
    }
    #pragma unroll
    for (int cg = 0; cg < 2; ++cg) {
        #pragma unroll
        for (int i = 0; i < 4; ++i) {
            int n = n0 + ((lane >> 4) << 2) + i;
            P[(size_t)n * 32 + cg * 16 + (lane & 15)] = acc[cg][i];
        }
    }
}

// ---------------- edge head, stage 2: out[e] = P[src][0:16] + P[dst][16:32] + b ----------
__global__ void k_edge_add(const float* __restrict__ P,
                           const int* __restrict__ srcArr, const int* __restrict__ dstArr,
                           const float* __restrict__ b_edge, float* __restrict__ out) {
    int e = blockIdx.x * 256 + threadIdx.x;
    if (e >= N_EDGES) return;
    int s = srcArr[e], d = dstArr[e];
    const float4* ps = (const float4*)(P + (size_t)s * 32);
    const float4* pd = (const float4*)(P + (size_t)d * 32 + 16);
    const float4* bb = (const float4*)b_edge;
    float4* po = (float4*)(out + (size_t)e * 16);
    #pragma unroll
    for (int i = 0; i < 4; ++i) {
        float4 a = ps[i], b = pd[i], c = bb[i];
        float4 rr;
        rr.x = a.x + b.x + c.x; rr.y = a.y + b.y + c.y;
        rr.z = a.z + b.z + c.z; rr.w = a.w + b.w + c.w;
        po[i] = rr;
    }
}

// ---------------- mean pool ----------------
__global__ void k_pool_sum(const unsigned short* __restrict__ x, const int* __restrict__ batch,
                           float* __restrict__ sums) {
    const int CH = 32;
    int w = threadIdx.x >> 6, lane = threadIdx.x & 63;
    int n0 = blockIdx.x * (4 * CH) + w * CH;
    if (n0 >= N_NODES) return;
    int n1 = n0 + CH; if (n1 > N_NODES) n1 = N_NODES;
    int d = lane * 4;
    float a0 = 0.f, a1 = 0.f, a2 = 0.f, a3 = 0.f;
    int gcur = batch[n0];
    for (int n = n0; n < n1; ++n) {
        int g = batch[n];
        if (g != gcur) {
            float* p = &sums[gcur * HID + d];
            atomicAdd(p + 0, a0); atomicAdd(p + 1, a1);
            atomicAdd(p + 2, a2); atomicAdd(p + 3, a3);
            a0 = a1 = a2 = a3 = 0.f; gcur = g;
        }
        ushort4 v = *(const ushort4*)&x[(size_t)n * HID + d];
        a0 += bf2f(v.x); a1 += bf2f(v.y); a2 += bf2f(v.z); a3 += bf2f(v.w);
    }
    float* p = &sums[gcur * HID + d];
    atomicAdd(p + 0, a0); atomicAdd(p + 1, a1);
    atomicAdd(p + 2, a2); atomicAdd(p + 3, a3);
}

__device__ __forceinline__ int lowerBound(const int* a, int n, int key) {
    int lo = 0, hi = n;
    while (lo < hi) { int mid = (lo + hi) >> 1; if (a[mid] < key) lo = mid + 1; else hi = mid; }
    return lo;
}

__global__ void k_pool_final(const float* __restrict__ sums, const int* __restrict__ batch,
                             float* __restrict__ out) {
    int g = blockIdx.x, d = threadIdx.x;
    int lo = lowerBound(batch, N_NODES, g);
    int hi = lowerBound(batch, N_NODES, g + 1);
    float cnt = (float)(hi - lo);
    out[(size_t)g * HID + d] = sums[g * HID + d] / fmaxf(cnt, 1.0f);
}

// ---------------- launcher ----------------
extern "C" void kernel_launch(void* const* d_in, const int* in_sizes, int n_in,
                              void* d_out, int out_size, void* d_ws, size_t ws_size,
                              hipStream_t stream) {
    const float* node_feats = (const float*)d_in[0];
    const int*   edge_index = (const int*)d_in[1];
    const int*   batch_idx  = (const int*)d_in[2];
    const float* W_rel0  = (const float*)d_in[3];
    const float* W_root0 = (const float*)d_in[4];
    const float* b0      = (const float*)d_in[5];
    const float* W_rel1  = (const float*)d_in[6];
    const float* W_root1 = (const float*)d_in[7];
    const float* b1      = (const float*)d_in[8];
    const float* W_rel2  = (const float*)d_in[9];
    const float* W_root2 = (const float*)d_in[10];
    const float* b2      = (const float*)d_in[11];
    const float* W_edge  = (const float*)d_in[12];
    const float* b_edge  = (const float*)d_in[13];

    const int* src = edge_index;
    const int* dst = edge_index + N_EDGES;

    char* ws = (char*)d_ws;
    size_t off = 0;
    auto alloc = [&](size_t bytes) -> char* {
        off = (off + 255) & ~(size_t)255;
        char* p = ws + off;
        off += bytes;
        return p;
    };
    unsigned short* xA    = (unsigned short*)alloc((size_t)N_NODES * HID * 2);  // x2
    unsigned short* xB    = (unsigned short*)alloc((size_t)N_NODES * HID * 2);  // x1 / x3
    unsigned short* Yrel  = (unsigned short*)alloc((size_t)N_NODES * HID * 2);
    unsigned short* Yroot = (unsigned short*)alloc((size_t)N_NODES * HID * 2);
    unsigned short* Wt0   = (unsigned short*)alloc(512 * 512 * 2);
    unsigned short* Wt1   = (unsigned short*)alloc(512 * 256 * 2);
    unsigned short* Wt2   = (unsigned short*)alloc(512 * 256 * 2);
    unsigned short* We2T  = (unsigned short*)alloc(32 * 256 * 2);
    float* P     = (float*)alloc((size_t)N_NODES * 32 * 4);
    int* counts  = (int*)alloc((size_t)N_NODES * 4);
    int* offsets = (int*)alloc((size_t)(N_NODES + 1) * 4);
    int* cur     = (int*)alloc((size_t)N_NODES * 4);
    int* csr     = (int*)alloc((size_t)N_EDGES * 4);
    int* bsum    = (int*)alloc(512 * 4);
    float* sums  = (float*)alloc(N_GRAPHS * HID * 4);

    const int nscan = (N_NODES + 255) / 256; // 391

    hipMemsetAsync(counts, 0, (size_t)N_NODES * 4, stream);
    hipMemsetAsync(sums, 0, N_GRAPHS * HID * 4, stream);

    // weight prep
    k_makeWt<<<dim3(8, 8), 256, 0, stream>>>(W_rel0, W_root0, Wt0, 512);
    k_makeWt<<<dim3(4, 8), 256, 0, stream>>>(W_rel1, W_root1, Wt1, 256);
    k_makeWt<<<dim3(4, 8), 256, 0, stream>>>(W_rel2, W_root2, Wt2, 256);
    k_makeWe2T<<<32, 256, 0, stream>>>(W_edge, We2T);

    // CSR build
    k_hist<<<(N_EDGES + 255) / 256, 256, 0, stream>>>(dst, counts);
    k_scanA<<<nscan, 256, 0, stream>>>(counts, bsum);
    k_scanB<<<1, 256, 0, stream>>>(bsum, nscan);
    k_scanC<<<nscan, 256, 0, stream>>>(counts, bsum, offsets, cur);
    k_fill<<<(N_EDGES + 255) / 256, 256, 0, stream>>>(src, dst, cur, csr);

    const int gemmGrid = ((N_NODES + 127) / 128) * 4; // 782*4 = 3128, %8==0
    // layer 0 (fp32 A via async DMA staging, cvt_pk on read)
    k_gemm0<<<gemmGrid, 256, 0, stream>>>(node_feats, Wt0, Yrel, Yroot, N_NODES);
    k_combine<<<(N_NODES + 3) / 4, 256, 0, stream>>>(Yrel, Yroot, offsets, csr, b0, xB);
    // layer 1
    k_gemm<<<gemmGrid, 256, 0, stream>>>(xB, Wt1, Yrel, Yroot, N_NODES, 256);
    k_combine<<<(N_NODES + 3) / 4, 256, 0, stream>>>(Yrel, Yroot, offsets, csr, b1, xA);
    // layer 2
    k_gemm<<<gemmGrid, 256, 0, stream>>>(xA, Wt2, Yrel, Yroot, N_NODES, 256);
    k_combine<<<(N_NODES + 3) / 4, 256, 0, stream>>>(Yrel, Yroot, offsets, csr, b2, xB);

    // edge head -> d_out[0 : 8M)
    float* out_logits = (float*)d_out;
    k_proj<<<(N_NODES / 16 + 3) / 4, 256, 0, stream>>>(xB, We2T, P);
    k_edge_add<<<(N_EDGES + 255) / 256, 256, 0, stream>>>(P, src, dst, b_edge, out_logits);

    // mean pool -> d_out[8M : 8M+16384)
    float* out_embed = (float*)d_out + (size_t)N_EDGES * NREL;
    k_pool_sum<<<(N_NODES + 127) / 128, 256, 0, stream>>>(xB, batch_idx, sums);
    k_pool_final<<<N_GRAPHS, 256, 0, stream>>>(sums, batch_idx, out_embed);
}